// Round 11
// baseline (1111.198 us; speedup 1.0000x reference)
//
#include <hip/hip_runtime.h>
#include <hip/hip_fp16.h>
#include <math.h>

#define N_NODES 100000
#define E_EDGES 1600000
#define F_IN 128
#define D_DIM 16
#define H_HEADS 8
#define HD 128
#define NEG_SLOPE 0.2f

#define SCAN_BLOCKS 256
#define SCAN_T 256
#define SCAN_CH ((N_NODES + SCAN_BLOCKS - 1) / SCAN_BLOCKS)   // 391

#define NTILES ((N_NODES + 63) / 64)        // 1563 node-tiles of 64

// ---------------------------------------------------------------------------
// Embedding: h0[n, 0..15] = x[n, :] @ W_emb + b_emb
// ---------------------------------------------------------------------------
__global__ __launch_bounds__(256) void embed_kernel(
        const float* __restrict__ x, const float* __restrict__ W,
        const float* __restrict__ b, float* __restrict__ h0) {
    __shared__ float Ws[F_IN * D_DIM];   // 8 KB
    __shared__ float bs[D_DIM];
    __shared__ float xs[16][F_IN + 1];
    int t = threadIdx.x;
    for (int i = t; i < F_IN * D_DIM; i += 256) Ws[i] = W[i];
    if (t < D_DIM) bs[t] = b[t];
    __syncthreads();
    for (int base = blockIdx.x * 16; base < N_NODES; base += gridDim.x * 16) {
        int cnt = min(16, N_NODES - base);
        __syncthreads();
        for (int i = t; i < cnt * F_IN; i += 256) {
            int nn = i >> 7, k = i & 127;
            xs[nn][k] = x[(size_t)(base + nn) * F_IN + k];
        }
        __syncthreads();
        int nn = t >> 4, c = t & 15;
        if (nn < cnt) {
            float a0 = 0.f, a1 = 0.f, a2 = 0.f, a3 = 0.f;
            #pragma unroll
            for (int k = 0; k < F_IN; k += 4) {
                a0 += xs[nn][k + 0] * Ws[(k + 0) * D_DIM + c];
                a1 += xs[nn][k + 1] * Ws[(k + 1) * D_DIM + c];
                a2 += xs[nn][k + 2] * Ws[(k + 2) * D_DIM + c];
                a3 += xs[nn][k + 3] * Ws[(k + 3) * D_DIM + c];
            }
            h0[(size_t)(base + nn) * D_DIM + c] = (a0 + a1) + (a2 + a3) + bs[c];
        }
    }
}

// ---------------------------------------------------------------------------
// Node transform as register-tiled GEMM: [N,K] @ [K,128] -> g (fp16), + attn
// dots (fp32, computed from fp32 accumulators before rounding).
// ---------------------------------------------------------------------------
template<int K>
__global__ __launch_bounds__(256) void transform_gemm_kernel(
        const float* __restrict__ h, const float* __restrict__ W,
        const float* __restrict__ att_s, const float* __restrict__ att_d,
        __half* __restrict__ g, float* __restrict__ a_src, float* __restrict__ a_dst) {
    __shared__ float Ws[K][64];          // K=128: 32 KB, K=16: 4 KB
    __shared__ float hs[64][K + 4];      // pad +4 floats: break row-bank stack
    int t = threadIdx.x;
    int cq = t & 15;                     // channel quad within half (0..15)
    int nq = t >> 4;                     // node quad (0..15)
    constexpr int KSH = (K == 128) ? 7 : 4;

    for (int item = blockIdx.x; item < NTILES * 2; item += gridDim.x) {
        int tile = item >> 1;
        int coff = (item & 1) << 6;                 // 0 or 64
        int nbase = tile << 6;
        __syncthreads();                            // protect prev iter reads
        // stage W column-half: K x 64
        for (int i = t; i < K * 64; i += 256)
            Ws[i >> 6][i & 63] = W[(size_t)(i >> 6) * HD + coff + (i & 63)];
        // stage 64 h rows (clamped in tail tile)
        for (int i = t; i < (K << 6); i += 256) {
            int r = i >> KSH, k = i & (K - 1);
            int n = nbase + r; if (n >= N_NODES) n = N_NODES - 1;
            hs[r][k] = h[(size_t)n * K + k];
        }
        __syncthreads();

        float acc[4][4] = {{0.f}};
        #pragma unroll 2
        for (int k = 0; k < K; k += 4) {
            float4 w0 = *(const float4*)&Ws[k + 0][cq << 2];
            float4 w1 = *(const float4*)&Ws[k + 1][cq << 2];
            float4 w2 = *(const float4*)&Ws[k + 2][cq << 2];
            float4 w3 = *(const float4*)&Ws[k + 3][cq << 2];
            #pragma unroll
            for (int j = 0; j < 4; ++j) {
                float4 hv = *(const float4*)&hs[(nq << 2) + j][k];
                acc[j][0] += hv.x * w0.x + hv.y * w1.x + hv.z * w2.x + hv.w * w3.x;
                acc[j][1] += hv.x * w0.y + hv.y * w1.y + hv.z * w2.y + hv.w * w3.y;
                acc[j][2] += hv.x * w0.z + hv.y * w1.z + hv.z * w2.z + hv.w * w3.z;
                acc[j][3] += hv.x * w0.w + hv.y * w1.w + hv.z * w2.w + hv.w * w3.w;
            }
        }

        int c0 = coff + (cq << 2);
        float as0 = att_s[c0], as1 = att_s[c0 + 1], as2 = att_s[c0 + 2], as3 = att_s[c0 + 3];
        float ad0 = att_d[c0], ad1 = att_d[c0 + 1], ad2 = att_d[c0 + 2], ad3 = att_d[c0 + 3];
        int head = c0 >> 4;
        #pragma unroll
        for (int j = 0; j < 4; ++j) {
            int n = nbase + (nq << 2) + j;
            float ps = acc[j][0] * as0 + acc[j][1] * as1 + acc[j][2] * as2 + acc[j][3] * as3;
            float pd = acc[j][0] * ad0 + acc[j][1] * ad1 + acc[j][2] * ad2 + acc[j][3] * ad3;
            ps += __shfl_xor(ps, 1); ps += __shfl_xor(ps, 2);
            pd += __shfl_xor(pd, 1); pd += __shfl_xor(pd, 2);
            if (n < N_NODES) {
                union { __half2 h2[2]; uint2 u; } pk;
                pk.h2[0] = __floats2half2_rn(acc[j][0], acc[j][1]);
                pk.h2[1] = __floats2half2_rn(acc[j][2], acc[j][3]);
                *(uint2*)&g[(size_t)n * HD + c0] = pk.u;
                if ((cq & 3) == 0) {
                    a_src[(size_t)n * H_HEADS + head] = ps;
                    a_dst[(size_t)n * H_HEADS + head] = pd;
                }
            }
        }
    }
}

// ---------------------------------------------------------------------------
// CSR build: histogram -> 3-phase multi-block scan -> scatter.
// ---------------------------------------------------------------------------
__global__ __launch_bounds__(256) void hist_kernel(
        const int* __restrict__ ei, int* __restrict__ deg) {
    int e = blockIdx.x * 256 + threadIdx.x;
    if (e < E_EDGES) atomicAdd(&deg[ei[E_EDGES + e]], 1);
}

__global__ __launch_bounds__(SCAN_T) void block_sum_kernel(
        const int* __restrict__ deg, int* __restrict__ bsum) {
    int b = blockIdx.x, t = threadIdx.x;
    int lo = b * SCAN_CH, hi = min(lo + SCAN_CH, N_NODES);
    int s = 0;
    for (int i = lo + t; i < hi; i += SCAN_T) s += deg[i];
    #pragma unroll
    for (int m = 1; m < 64; m <<= 1) s += __shfl_xor(s, m);
    __shared__ int ws[SCAN_T / 64];
    if ((t & 63) == 0) ws[t >> 6] = s;
    __syncthreads();
    if (t == 0) {
        int tot = 0;
        #pragma unroll
        for (int w = 0; w < SCAN_T / 64; ++w) tot += ws[w];
        bsum[b] = tot;
    }
}

__global__ __launch_bounds__(SCAN_BLOCKS) void offset_scan_kernel(
        const int* __restrict__ bsum, int* __restrict__ boff) {
    __shared__ int tmp[SCAN_BLOCKS];
    int t = threadIdx.x;
    int v = bsum[t];
    tmp[t] = v;
    __syncthreads();
    int val = v;
    for (int off = 1; off < SCAN_BLOCKS; off <<= 1) {
        int o = (t >= off) ? tmp[t - off] : 0;
        __syncthreads();
        val += o;
        tmp[t] = val;
        __syncthreads();
    }
    boff[t] = val - v;    // exclusive
}

__global__ __launch_bounds__(SCAN_T) void row_ptr_kernel(
        const int* __restrict__ deg, const int* __restrict__ boff,
        int* __restrict__ row_ptr, int* __restrict__ fill) {
    int b = blockIdx.x, t = threadIdx.x;
    int lo = b * SCAN_CH, hi = min(lo + SCAN_CH, N_NODES);
    __shared__ int tmp[SCAN_T];
    __shared__ int carry;
    if (t == 0) carry = boff[b];
    __syncthreads();
    for (int base = lo; base < hi; base += SCAN_T) {
        int i = base + t;
        int v = (i < hi) ? deg[i] : 0;
        tmp[t] = v;
        __syncthreads();
        int val = v;
        for (int off = 1; off < SCAN_T; off <<= 1) {
            int o = (t >= off) ? tmp[t - off] : 0;
            __syncthreads();
            val += o;
            tmp[t] = val;
            __syncthreads();
        }
        int excl = val - v + carry;
        if (i < hi) { row_ptr[i] = excl; fill[i] = excl; }
        __syncthreads();
        if (t == SCAN_T - 1) carry = carry + val;
        __syncthreads();
    }
    if (b == SCAN_BLOCKS - 1 && t == 0) row_ptr[N_NODES] = carry;  // == E
}

__global__ __launch_bounds__(256) void scatter_kernel(
        const int* __restrict__ ei, int* __restrict__ fill,
        int* __restrict__ col) {
    int e = blockIdx.x * 256 + threadIdx.x;
    if (e < E_EDGES) {
        int d = ei[E_EDGES + e];
        int p = atomicAdd(&fill[d], 1);
        col[p] = ei[e];
    }
}

// ---------------------------------------------------------------------------
// Degree-bucket counting sort of dst nodes (64 buckets). Waves then process
// 4 near-equal-degree dsts -> minimal max(deg) slack in the aggr loop.
// ---------------------------------------------------------------------------
__global__ __launch_bounds__(256) void bucket_hist_kernel(
        const int* __restrict__ deg, int* __restrict__ bhist) {
    int n = blockIdx.x * 256 + threadIdx.x;
    if (n < N_NODES) atomicAdd(&bhist[min(deg[n], 63)], 1);
}

__global__ __launch_bounds__(64) void bucket_scan_kernel(
        const int* __restrict__ bhist, int* __restrict__ bfill) {
    int lane = threadIdx.x;              // one wave of 64
    int v = bhist[lane];
    int val = v;
    #pragma unroll
    for (int off = 1; off < 64; off <<= 1) {
        int o = __shfl_up(val, off);
        val += (lane >= off) ? o : 0;
    }
    bfill[lane] = val - v;               // exclusive offsets
}

__global__ __launch_bounds__(256) void bucket_scatter_kernel(
        const int* __restrict__ deg, int* __restrict__ bfill,
        int* __restrict__ perm) {
    int n = blockIdx.x * 256 + threadIdx.x;
    if (n < N_NODES) {
        int p = atomicAdd(&bfill[min(deg[n], 63)], 1);
        perm[p] = n;
    }
}

// ---------------------------------------------------------------------------
// Fused GAT aggregation over CSR: 4 dst per wave (one per 16-lane group),
// dsts assigned via degree-sorted perm (near-equal deg within a wave).
// Edge loop unrolled x4: 4 independent {a_src, uint4 row} gather pairs per
// group in flight (latency-hiding; round-10 showed VALU idle at 27%).
// ---------------------------------------------------------------------------
template<bool FUSE>
__global__ __launch_bounds__(256) void gat_aggr_csr_kernel(
        const int* __restrict__ perm,
        const int* __restrict__ row_ptr, const int* __restrict__ col,
        const float* __restrict__ a_src, const float* __restrict__ a_dst,
        const __half* __restrict__ g, const float* __restrict__ bias,
        float* __restrict__ out,
        const float* __restrict__ Wy1, const float* __restrict__ by1,
        const float* __restrict__ Wy0, const float* __restrict__ by0,
        const float* __restrict__ Wc1, const float* __restrict__ bc1,
        const float* __restrict__ Wc2, const float* __restrict__ bc2) {
    int wv = threadIdx.x >> 6, lane = threadIdx.x & 63;
    int grp = lane >> 4;                 // dst slot within wave
    int sub = lane & 15;                 // channel slice (8*sub..8*sub+7)
    int hh  = sub >> 1;                  // head 0..7
    int slot = blockIdx.x * 16 + wv * 4 + grp;
    bool dvalid = slot < N_NODES;
    int d = perm[dvalid ? slot : N_NODES - 1];
    int dd = d;

    int i0 = row_ptr[dd], end = row_ptr[dd + 1];
    int deg = dvalid ? (end - i0) : 0;
    float ad = a_dst[dd * 8 + hh];

    // self-loop folded into accumulator init (group-local, no reduction)
    float acc[8];
    float den;
    {
        float a = a_src[dd * 8 + hh] + ad;
        a = fmaxf(a, NEG_SLOPE * a);
        float w = __expf(a);
        uint4 rv = *(const uint4*)(g + (size_t)dd * HD + (sub << 3));
        float2 f0 = __half22float2(*(__half2*)&rv.x);
        float2 f1 = __half22float2(*(__half2*)&rv.y);
        float2 f2 = __half22float2(*(__half2*)&rv.z);
        float2 f3 = __half22float2(*(__half2*)&rv.w);
        acc[0] = w * f0.x; acc[1] = w * f0.y;
        acc[2] = w * f1.x; acc[3] = w * f1.y;
        acc[4] = w * f2.x; acc[5] = w * f2.y;
        acc[6] = w * f3.x; acc[7] = w * f3.y;
        den = w;
    }

    // wave-uniform loop bound: max degree over the wave's 4 dsts
    int md = deg;
    md = max(md, __shfl_xor(md, 16));
    md = max(md, __shfl_xor(md, 32));

    int colv = 0;
    #define EDGE_K(EL)                                                       \
    {                                                                        \
        int el_ = (EL);                                                      \
        int s = __shfl(colv, (grp << 4) | (el_ & 15));                       \
        float a = a_src[s * 8 + hh] + ad;                                    \
        a = fmaxf(a, NEG_SLOPE * a);                                         \
        float w = (el_ < deg) ? __expf(a) : 0.f;                             \
        uint4 rv = *(const uint4*)(g + (size_t)s * HD + (sub << 3));         \
        float2 f0 = __half22float2(*(__half2*)&rv.x);                        \
        float2 f1 = __half22float2(*(__half2*)&rv.y);                        \
        float2 f2 = __half22float2(*(__half2*)&rv.z);                        \
        float2 f3 = __half22float2(*(__half2*)&rv.w);                        \
        acc[0] += w * f0.x; acc[1] += w * f0.y;                              \
        acc[2] += w * f1.x; acc[3] += w * f1.y;                              \
        acc[4] += w * f2.x; acc[5] += w * f2.y;                              \
        acc[6] += w * f3.x; acc[7] += w * f3.y;                              \
        den += w;                                                            \
    }

    for (int el = 0; el < md; el += 4) {
        if ((el & 15) == 0) {             // coalesced window refill (uniform)
            int ci = i0 + el + sub;
            ci = min(ci, end - 1);
            ci = max(ci, 0);
            colv = col[ci];
        }
        EDGE_K(el);
        EDGE_K(el + 1);
        EDGE_K(el + 2);
        EDGE_K(el + 3);
    }
    #undef EDGE_K

    float inv = 1.f / (den + 1e-16f);
    int c0 = sub << 3;
    float h[8];
    #pragma unroll
    for (int k = 0; k < 8; ++k) h[k] = acc[k] * inv + bias[c0 + k];

    if (!FUSE) {
        if (dvalid) {
            *(float4*)&out[(size_t)d * HD + c0] =
                make_float4(h[0], h[1], h[2], h[3]);
            *(float4*)&out[(size_t)d * HD + c0 + 4] =
                make_float4(h[4], h[5], h[6], h[7]);
        }
    } else {
        // causal effect: width-16 reduction within the group
        float p = 0.f;
        #pragma unroll
        for (int k = 0; k < 8; ++k)
            p += h[k] * (Wy1[c0 + k] - Wy0[c0 + k]);
        p += __shfl_xor(p, 1); p += __shfl_xor(p, 2);
        p += __shfl_xor(p, 4); p += __shfl_xor(p, 8);
        // classifier MLP
        float acc2 = 0.f;
        #pragma unroll
        for (int j = 0; j < D_DIM; ++j) {
            float q = 0.f;
            #pragma unroll
            for (int k = 0; k < 8; ++k)
                q += h[k] * Wc1[(c0 + k) * D_DIM + j];
            q += __shfl_xor(q, 1); q += __shfl_xor(q, 2);
            q += __shfl_xor(q, 4); q += __shfl_xor(q, 8);
            float z = q + bc1[j];
            z = (z > 0.f) ? z : 0.f;
            acc2 += z * Wc2[j];
        }
        if (sub == 0 && dvalid) {
            out[d] = p + by1[0] - by0[0];
            out[N_NODES + d] = 1.f / (1.f + __expf(-(acc2 + bc2[0])));
        }
    }
}

// ---------------------------------------------------------------------------
extern "C" void kernel_launch(void* const* d_in, const int* in_sizes, int n_in,
                              void* d_out, int out_size, void* d_ws, size_t ws_size,
                              hipStream_t stream) {
    const float* x     = (const float*)d_in[0];
    const int*   ei    = (const int*)  d_in[1];
    const float* W_emb = (const float*)d_in[2];
    const float* b_emb = (const float*)d_in[3];
    const float* W0    = (const float*)d_in[4];
    const float* as0   = (const float*)d_in[5];
    const float* ad0   = (const float*)d_in[6];
    const float* b0    = (const float*)d_in[7];
    const float* W1    = (const float*)d_in[8];
    const float* as1   = (const float*)d_in[9];
    const float* ad1   = (const float*)d_in[10];
    const float* b1    = (const float*)d_in[11];
    const float* Wy1   = (const float*)d_in[12];
    const float* by1   = (const float*)d_in[13];
    const float* Wy0   = (const float*)d_in[14];
    const float* by0   = (const float*)d_in[15];
    const float* Wc1   = (const float*)d_in[16];
    const float* bc1   = (const float*)d_in[17];
    const float* Wc2   = (const float*)d_in[18];
    const float* bc2   = (const float*)d_in[19];
    float* out = (float*)d_out;

    float* ws    = (float*)d_ws;
    __half* gH   = (__half*)ws;                          // N*128 halves (25.6MB)
    float* bufH  = (float*)(ws + (size_t)N_NODES * HD / 2 + 64);  // N*128 f32
    float* h0    = bufH + (size_t)N_NODES * HD;          // N*16
    float* a_s   = h0   + (size_t)N_NODES * D_DIM;       // N*8
    float* a_d   = a_s  + (size_t)N_NODES * H_HEADS;     // N*8
    int*   deg     = (int*)(a_d + (size_t)N_NODES * H_HEADS);  // N
    int*   fill    = deg + N_NODES;                            // N
    int*   row_ptr = fill + N_NODES;                           // N+1
    int*   bsum    = row_ptr + (N_NODES + 1);                  // 256
    int*   boff    = bsum + SCAN_BLOCKS;                       // 256
    int*   bhist   = boff + SCAN_BLOCKS;                       // 64
    int*   bfill   = bhist + 64;                               // 64
    int*   perm    = bfill + 64;                               // N
    int*   col     = perm + N_NODES;                           // E

    int edgeBlocks = (E_EDGES + 255) / 256;
    int nodeBlocks = (N_NODES + 255) / 256;
    int aggrBlocks = (N_NODES + 15) / 16;

    // ----- CSR build (once; reused by both layers) -----
    hipMemsetAsync(deg, 0, (size_t)N_NODES * sizeof(int), stream);
    hipMemsetAsync(bhist, 0, 64 * sizeof(int), stream);
    hipLaunchKernelGGL(hist_kernel, dim3(edgeBlocks), dim3(256), 0, stream, ei, deg);
    hipLaunchKernelGGL(block_sum_kernel, dim3(SCAN_BLOCKS), dim3(SCAN_T), 0, stream,
                       deg, bsum);
    hipLaunchKernelGGL(offset_scan_kernel, dim3(1), dim3(SCAN_BLOCKS), 0, stream,
                       bsum, boff);
    hipLaunchKernelGGL(row_ptr_kernel, dim3(SCAN_BLOCKS), dim3(SCAN_T), 0, stream,
                       deg, boff, row_ptr, fill);
    hipLaunchKernelGGL(scatter_kernel, dim3(edgeBlocks), dim3(256), 0, stream,
                       ei, fill, col);

    // ----- degree-bucket sort of dsts (load balance for aggr waves) -----
    hipLaunchKernelGGL(bucket_hist_kernel, dim3(nodeBlocks), dim3(256), 0, stream,
                       deg, bhist);
    hipLaunchKernelGGL(bucket_scan_kernel, dim3(1), dim3(64), 0, stream,
                       bhist, bfill);
    hipLaunchKernelGGL(bucket_scatter_kernel, dim3(nodeBlocks), dim3(256), 0, stream,
                       deg, bfill, perm);

    // ----- Embedding -----
    hipLaunchKernelGGL(embed_kernel, dim3(512), dim3(256), 0, stream,
                       x, W_emb, b_emb, h0);

    // ----- GAT layer 0 (K = 16) -----
    hipLaunchKernelGGL(transform_gemm_kernel<16>, dim3(2048), dim3(256), 0, stream,
                       h0, W0, as0, ad0, gH, a_s, a_d);
    hipLaunchKernelGGL(gat_aggr_csr_kernel<false>, dim3(aggrBlocks), dim3(256), 0, stream,
                       perm, row_ptr, col, a_s, a_d, gH, b0, bufH,
                       (const float*)nullptr, (const float*)nullptr,
                       (const float*)nullptr, (const float*)nullptr,
                       (const float*)nullptr, (const float*)nullptr,
                       (const float*)nullptr, (const float*)nullptr);

    // ----- GAT layer 1 (K = 128) + fused heads -----
    hipLaunchKernelGGL(transform_gemm_kernel<128>, dim3(1024), dim3(256), 0, stream,
                       bufH, W1, as1, ad1, gH, a_s, a_d);
    hipLaunchKernelGGL(gat_aggr_csr_kernel<true>, dim3(aggrBlocks), dim3(256), 0, stream,
                       perm, row_ptr, col, a_s, a_d, gH, b1, out,
                       Wy1, by1, Wy0, by0, Wc1, bc1, Wc2, bc2);
}

// Round 12
// 560.790 us; speedup vs baseline: 1.9815x; 1.9815x over previous
//
#include <hip/hip_runtime.h>
#include <hip/hip_fp16.h>
#include <math.h>

#define N_NODES 100000
#define E_EDGES 1600000
#define F_IN 128
#define D_DIM 16
#define H_HEADS 8
#define HD 128
#define NEG_SLOPE 0.2f

#define SCAN_BLOCKS 256
#define SCAN_T 256
#define SCAN_CH ((N_NODES + SCAN_BLOCKS - 1) / SCAN_BLOCKS)   // 391

#define NTILES ((N_NODES + 63) / 64)        // 1563 node-tiles of 64

// ---------------------------------------------------------------------------
// Embedding: h0[n, 0..15] = x[n, :] @ W_emb + b_emb
// ---------------------------------------------------------------------------
__global__ __launch_bounds__(256) void embed_kernel(
        const float* __restrict__ x, const float* __restrict__ W,
        const float* __restrict__ b, float* __restrict__ h0) {
    __shared__ float Ws[F_IN * D_DIM];   // 8 KB
    __shared__ float bs[D_DIM];
    __shared__ float xs[16][F_IN + 1];
    int t = threadIdx.x;
    for (int i = t; i < F_IN * D_DIM; i += 256) Ws[i] = W[i];
    if (t < D_DIM) bs[t] = b[t];
    __syncthreads();
    for (int base = blockIdx.x * 16; base < N_NODES; base += gridDim.x * 16) {
        int cnt = min(16, N_NODES - base);
        __syncthreads();
        for (int i = t; i < cnt * F_IN; i += 256) {
            int nn = i >> 7, k = i & 127;
            xs[nn][k] = x[(size_t)(base + nn) * F_IN + k];
        }
        __syncthreads();
        int nn = t >> 4, c = t & 15;
        if (nn < cnt) {
            float a0 = 0.f, a1 = 0.f, a2 = 0.f, a3 = 0.f;
            #pragma unroll
            for (int k = 0; k < F_IN; k += 4) {
                a0 += xs[nn][k + 0] * Ws[(k + 0) * D_DIM + c];
                a1 += xs[nn][k + 1] * Ws[(k + 1) * D_DIM + c];
                a2 += xs[nn][k + 2] * Ws[(k + 2) * D_DIM + c];
                a3 += xs[nn][k + 3] * Ws[(k + 3) * D_DIM + c];
            }
            h0[(size_t)(base + nn) * D_DIM + c] = (a0 + a1) + (a2 + a3) + bs[c];
        }
    }
}

// ---------------------------------------------------------------------------
// Node transform as register-tiled GEMM: [N,K] @ [K,128] -> g (fp16), + attn
// dots (fp32, computed from fp32 accumulators before rounding).
// ---------------------------------------------------------------------------
template<int K>
__global__ __launch_bounds__(256) void transform_gemm_kernel(
        const float* __restrict__ h, const float* __restrict__ W,
        const float* __restrict__ att_s, const float* __restrict__ att_d,
        __half* __restrict__ g, float* __restrict__ a_src, float* __restrict__ a_dst) {
    __shared__ float Ws[K][64];          // K=128: 32 KB, K=16: 4 KB
    __shared__ float hs[64][K + 4];      // pad +4 floats: break row-bank stack
    int t = threadIdx.x;
    int cq = t & 15;                     // channel quad within half (0..15)
    int nq = t >> 4;                     // node quad (0..15)
    constexpr int KSH = (K == 128) ? 7 : 4;

    for (int item = blockIdx.x; item < NTILES * 2; item += gridDim.x) {
        int tile = item >> 1;
        int coff = (item & 1) << 6;                 // 0 or 64
        int nbase = tile << 6;
        __syncthreads();                            // protect prev iter reads
        // stage W column-half: K x 64
        for (int i = t; i < K * 64; i += 256)
            Ws[i >> 6][i & 63] = W[(size_t)(i >> 6) * HD + coff + (i & 63)];
        // stage 64 h rows (clamped in tail tile)
        for (int i = t; i < (K << 6); i += 256) {
            int r = i >> KSH, k = i & (K - 1);
            int n = nbase + r; if (n >= N_NODES) n = N_NODES - 1;
            hs[r][k] = h[(size_t)n * K + k];
        }
        __syncthreads();

        float acc[4][4] = {{0.f}};
        #pragma unroll 2
        for (int k = 0; k < K; k += 4) {
            float4 w0 = *(const float4*)&Ws[k + 0][cq << 2];
            float4 w1 = *(const float4*)&Ws[k + 1][cq << 2];
            float4 w2 = *(const float4*)&Ws[k + 2][cq << 2];
            float4 w3 = *(const float4*)&Ws[k + 3][cq << 2];
            #pragma unroll
            for (int j = 0; j < 4; ++j) {
                float4 hv = *(const float4*)&hs[(nq << 2) + j][k];
                acc[j][0] += hv.x * w0.x + hv.y * w1.x + hv.z * w2.x + hv.w * w3.x;
                acc[j][1] += hv.x * w0.y + hv.y * w1.y + hv.z * w2.y + hv.w * w3.y;
                acc[j][2] += hv.x * w0.z + hv.y * w1.z + hv.z * w2.z + hv.w * w3.z;
                acc[j][3] += hv.x * w0.w + hv.y * w1.w + hv.z * w2.w + hv.w * w3.w;
            }
        }

        int c0 = coff + (cq << 2);
        float as0 = att_s[c0], as1 = att_s[c0 + 1], as2 = att_s[c0 + 2], as3 = att_s[c0 + 3];
        float ad0 = att_d[c0], ad1 = att_d[c0 + 1], ad2 = att_d[c0 + 2], ad3 = att_d[c0 + 3];
        int head = c0 >> 4;
        #pragma unroll
        for (int j = 0; j < 4; ++j) {
            int n = nbase + (nq << 2) + j;
            float ps = acc[j][0] * as0 + acc[j][1] * as1 + acc[j][2] * as2 + acc[j][3] * as3;
            float pd = acc[j][0] * ad0 + acc[j][1] * ad1 + acc[j][2] * ad2 + acc[j][3] * ad3;
            ps += __shfl_xor(ps, 1); ps += __shfl_xor(ps, 2);
            pd += __shfl_xor(pd, 1); pd += __shfl_xor(pd, 2);
            if (n < N_NODES) {
                union { __half2 h2[2]; uint2 u; } pk;
                pk.h2[0] = __floats2half2_rn(acc[j][0], acc[j][1]);
                pk.h2[1] = __floats2half2_rn(acc[j][2], acc[j][3]);
                *(uint2*)&g[(size_t)n * HD + c0] = pk.u;
                if ((cq & 3) == 0) {
                    a_src[(size_t)n * H_HEADS + head] = ps;
                    a_dst[(size_t)n * H_HEADS + head] = pd;
                }
            }
        }
    }
}

// ---------------------------------------------------------------------------
// CSR build: histogram -> 3-phase multi-block scan -> scatter.
// ---------------------------------------------------------------------------
__global__ __launch_bounds__(256) void hist_kernel(
        const int* __restrict__ ei, int* __restrict__ deg) {
    int e = blockIdx.x * 256 + threadIdx.x;
    if (e < E_EDGES) atomicAdd(&deg[ei[E_EDGES + e]], 1);
}

__global__ __launch_bounds__(SCAN_T) void block_sum_kernel(
        const int* __restrict__ deg, int* __restrict__ bsum) {
    int b = blockIdx.x, t = threadIdx.x;
    int lo = b * SCAN_CH, hi = min(lo + SCAN_CH, N_NODES);
    int s = 0;
    for (int i = lo + t; i < hi; i += SCAN_T) s += deg[i];
    #pragma unroll
    for (int m = 1; m < 64; m <<= 1) s += __shfl_xor(s, m);
    __shared__ int ws[SCAN_T / 64];
    if ((t & 63) == 0) ws[t >> 6] = s;
    __syncthreads();
    if (t == 0) {
        int tot = 0;
        #pragma unroll
        for (int w = 0; w < SCAN_T / 64; ++w) tot += ws[w];
        bsum[b] = tot;
    }
}

__global__ __launch_bounds__(SCAN_BLOCKS) void offset_scan_kernel(
        const int* __restrict__ bsum, int* __restrict__ boff) {
    __shared__ int tmp[SCAN_BLOCKS];
    int t = threadIdx.x;
    int v = bsum[t];
    tmp[t] = v;
    __syncthreads();
    int val = v;
    for (int off = 1; off < SCAN_BLOCKS; off <<= 1) {
        int o = (t >= off) ? tmp[t - off] : 0;
        __syncthreads();
        val += o;
        tmp[t] = val;
        __syncthreads();
    }
    boff[t] = val - v;    // exclusive
}

__global__ __launch_bounds__(SCAN_T) void row_ptr_kernel(
        const int* __restrict__ deg, const int* __restrict__ boff,
        int* __restrict__ row_ptr, int* __restrict__ fill) {
    int b = blockIdx.x, t = threadIdx.x;
    int lo = b * SCAN_CH, hi = min(lo + SCAN_CH, N_NODES);
    __shared__ int tmp[SCAN_T];
    __shared__ int carry;
    if (t == 0) carry = boff[b];
    __syncthreads();
    for (int base = lo; base < hi; base += SCAN_T) {
        int i = base + t;
        int v = (i < hi) ? deg[i] : 0;
        tmp[t] = v;
        __syncthreads();
        int val = v;
        for (int off = 1; off < SCAN_T; off <<= 1) {
            int o = (t >= off) ? tmp[t - off] : 0;
            __syncthreads();
            val += o;
            tmp[t] = val;
            __syncthreads();
        }
        int excl = val - v + carry;
        if (i < hi) { row_ptr[i] = excl; fill[i] = excl; }
        __syncthreads();
        if (t == SCAN_T - 1) carry = carry + val;
        __syncthreads();
    }
    if (b == SCAN_BLOCKS - 1 && t == 0) row_ptr[N_NODES] = carry;  // == E
}

__global__ __launch_bounds__(256) void scatter_kernel(
        const int* __restrict__ ei, int* __restrict__ fill,
        int* __restrict__ col) {
    int e = blockIdx.x * 256 + threadIdx.x;
    if (e < E_EDGES) {
        int d = ei[E_EDGES + e];
        int p = atomicAdd(&fill[d], 1);
        col[p] = ei[e];
    }
}

// ---------------------------------------------------------------------------
// Degree-bucket counting sort of dst nodes, CONTENTION-FREE version:
// per-block LDS histograms -> global (bucket-major) counts -> one-block scan
// -> scatter with LDS-atomic local offsets. Zero global atomics.
// (Round 11's global-atomic version: 2 x ~270 us of pure RMW serialization.)
// ---------------------------------------------------------------------------
__global__ __launch_bounds__(256) void bucket_hist_kernel(
        const int* __restrict__ deg, int* __restrict__ bcount) {
    __shared__ int lh[64];
    int b = blockIdx.x, t = threadIdx.x;
    if (t < 64) lh[t] = 0;
    __syncthreads();
    int lo = b * SCAN_CH, hi = min(lo + SCAN_CH, N_NODES);
    for (int i = lo + t; i < hi; i += 256)
        atomicAdd(&lh[min(deg[i], 63)], 1);
    __syncthreads();
    if (t < 64) bcount[t * SCAN_BLOCKS + b] = lh[t];   // bucket-major
}

__global__ __launch_bounds__(1024) void bucket_scan_kernel(
        const int* __restrict__ bcount, int* __restrict__ boffs) {
    __shared__ int part[1024];
    int t = threadIdx.x;
    int base = t * 16;                       // 16384 = 64 buckets x 256 blocks
    int v[16]; int s = 0;
    #pragma unroll
    for (int k = 0; k < 16; ++k) { v[k] = bcount[base + k]; s += v[k]; }
    part[t] = s;
    __syncthreads();
    int val = s;
    for (int off = 1; off < 1024; off <<= 1) {
        int o = (t >= off) ? part[t - off] : 0;
        __syncthreads();
        val += o;
        part[t] = val;
        __syncthreads();
    }
    int run = val - s;                       // exclusive prefix of this chunk
    #pragma unroll
    for (int k = 0; k < 16; ++k) { boffs[base + k] = run; run += v[k]; }
}

__global__ __launch_bounds__(256) void bucket_scatter_kernel(
        const int* __restrict__ deg, const int* __restrict__ boffs,
        int* __restrict__ perm) {
    __shared__ int lbase[64];
    int b = blockIdx.x, t = threadIdx.x;
    if (t < 64) lbase[t] = boffs[t * SCAN_BLOCKS + b];
    __syncthreads();
    int lo = b * SCAN_CH, hi = min(lo + SCAN_CH, N_NODES);
    for (int i = lo + t; i < hi; i += 256) {
        int p = atomicAdd(&lbase[min(deg[i], 63)], 1);   // LDS atomic only
        perm[p] = i;
    }
}

// ---------------------------------------------------------------------------
// Fused GAT aggregation over CSR: 4 dst per wave (one per 16-lane group),
// dsts assigned via degree-sorted perm (near-equal deg within a wave).
// Edge loop unrolled x4: 4 independent {a_src, uint4 row} gather pairs per
// group in flight (latency-hiding; round-10 showed VALU idle at 27%).
// ---------------------------------------------------------------------------
template<bool FUSE>
__global__ __launch_bounds__(256) void gat_aggr_csr_kernel(
        const int* __restrict__ perm,
        const int* __restrict__ row_ptr, const int* __restrict__ col,
        const float* __restrict__ a_src, const float* __restrict__ a_dst,
        const __half* __restrict__ g, const float* __restrict__ bias,
        float* __restrict__ out,
        const float* __restrict__ Wy1, const float* __restrict__ by1,
        const float* __restrict__ Wy0, const float* __restrict__ by0,
        const float* __restrict__ Wc1, const float* __restrict__ bc1,
        const float* __restrict__ Wc2, const float* __restrict__ bc2) {
    int wv = threadIdx.x >> 6, lane = threadIdx.x & 63;
    int grp = lane >> 4;                 // dst slot within wave
    int sub = lane & 15;                 // channel slice (8*sub..8*sub+7)
    int hh  = sub >> 1;                  // head 0..7
    int slot = blockIdx.x * 16 + wv * 4 + grp;
    bool dvalid = slot < N_NODES;
    int d = perm[dvalid ? slot : N_NODES - 1];
    int dd = d;

    int i0 = row_ptr[dd], end = row_ptr[dd + 1];
    int deg = dvalid ? (end - i0) : 0;
    float ad = a_dst[dd * 8 + hh];

    // self-loop folded into accumulator init (group-local, no reduction)
    float acc[8];
    float den;
    {
        float a = a_src[dd * 8 + hh] + ad;
        a = fmaxf(a, NEG_SLOPE * a);
        float w = __expf(a);
        uint4 rv = *(const uint4*)(g + (size_t)dd * HD + (sub << 3));
        float2 f0 = __half22float2(*(__half2*)&rv.x);
        float2 f1 = __half22float2(*(__half2*)&rv.y);
        float2 f2 = __half22float2(*(__half2*)&rv.z);
        float2 f3 = __half22float2(*(__half2*)&rv.w);
        acc[0] = w * f0.x; acc[1] = w * f0.y;
        acc[2] = w * f1.x; acc[3] = w * f1.y;
        acc[4] = w * f2.x; acc[5] = w * f2.y;
        acc[6] = w * f3.x; acc[7] = w * f3.y;
        den = w;
    }

    // wave-uniform loop bound: max degree over the wave's 4 dsts
    int md = deg;
    md = max(md, __shfl_xor(md, 16));
    md = max(md, __shfl_xor(md, 32));

    int colv = 0;
    #define EDGE_K(EL)                                                       \
    {                                                                        \
        int el_ = (EL);                                                      \
        int s = __shfl(colv, (grp << 4) | (el_ & 15));                       \
        float a = a_src[s * 8 + hh] + ad;                                    \
        a = fmaxf(a, NEG_SLOPE * a);                                         \
        float w = (el_ < deg) ? __expf(a) : 0.f;                             \
        uint4 rv = *(const uint4*)(g + (size_t)s * HD + (sub << 3));         \
        float2 f0 = __half22float2(*(__half2*)&rv.x);                        \
        float2 f1 = __half22float2(*(__half2*)&rv.y);                        \
        float2 f2 = __half22float2(*(__half2*)&rv.z);                        \
        float2 f3 = __half22float2(*(__half2*)&rv.w);                        \
        acc[0] += w * f0.x; acc[1] += w * f0.y;                              \
        acc[2] += w * f1.x; acc[3] += w * f1.y;                              \
        acc[4] += w * f2.x; acc[5] += w * f2.y;                              \
        acc[6] += w * f3.x; acc[7] += w * f3.y;                              \
        den += w;                                                            \
    }

    for (int el = 0; el < md; el += 4) {
        if ((el & 15) == 0) {             // coalesced window refill (uniform)
            int ci = i0 + el + sub;
            ci = min(ci, end - 1);
            ci = max(ci, 0);
            colv = col[ci];
        }
        EDGE_K(el);
        EDGE_K(el + 1);
        EDGE_K(el + 2);
        EDGE_K(el + 3);
    }
    #undef EDGE_K

    float inv = 1.f / (den + 1e-16f);
    int c0 = sub << 3;
    float h[8];
    #pragma unroll
    for (int k = 0; k < 8; ++k) h[k] = acc[k] * inv + bias[c0 + k];

    if (!FUSE) {
        if (dvalid) {
            *(float4*)&out[(size_t)d * HD + c0] =
                make_float4(h[0], h[1], h[2], h[3]);
            *(float4*)&out[(size_t)d * HD + c0 + 4] =
                make_float4(h[4], h[5], h[6], h[7]);
        }
    } else {
        // causal effect: width-16 reduction within the group
        float p = 0.f;
        #pragma unroll
        for (int k = 0; k < 8; ++k)
            p += h[k] * (Wy1[c0 + k] - Wy0[c0 + k]);
        p += __shfl_xor(p, 1); p += __shfl_xor(p, 2);
        p += __shfl_xor(p, 4); p += __shfl_xor(p, 8);
        // classifier MLP
        float acc2 = 0.f;
        #pragma unroll
        for (int j = 0; j < D_DIM; ++j) {
            float q = 0.f;
            #pragma unroll
            for (int k = 0; k < 8; ++k)
                q += h[k] * Wc1[(c0 + k) * D_DIM + j];
            q += __shfl_xor(q, 1); q += __shfl_xor(q, 2);
            q += __shfl_xor(q, 4); q += __shfl_xor(q, 8);
            float z = q + bc1[j];
            z = (z > 0.f) ? z : 0.f;
            acc2 += z * Wc2[j];
        }
        if (sub == 0 && dvalid) {
            out[d] = p + by1[0] - by0[0];
            out[N_NODES + d] = 1.f / (1.f + __expf(-(acc2 + bc2[0])));
        }
    }
}

// ---------------------------------------------------------------------------
extern "C" void kernel_launch(void* const* d_in, const int* in_sizes, int n_in,
                              void* d_out, int out_size, void* d_ws, size_t ws_size,
                              hipStream_t stream) {
    const float* x     = (const float*)d_in[0];
    const int*   ei    = (const int*)  d_in[1];
    const float* W_emb = (const float*)d_in[2];
    const float* b_emb = (const float*)d_in[3];
    const float* W0    = (const float*)d_in[4];
    const float* as0   = (const float*)d_in[5];
    const float* ad0   = (const float*)d_in[6];
    const float* b0    = (const float*)d_in[7];
    const float* W1    = (const float*)d_in[8];
    const float* as1   = (const float*)d_in[9];
    const float* ad1   = (const float*)d_in[10];
    const float* b1    = (const float*)d_in[11];
    const float* Wy1   = (const float*)d_in[12];
    const float* by1   = (const float*)d_in[13];
    const float* Wy0   = (const float*)d_in[14];
    const float* by0   = (const float*)d_in[15];
    const float* Wc1   = (const float*)d_in[16];
    const float* bc1   = (const float*)d_in[17];
    const float* Wc2   = (const float*)d_in[18];
    const float* bc2   = (const float*)d_in[19];
    float* out = (float*)d_out;

    float* ws    = (float*)d_ws;
    __half* gH   = (__half*)ws;                          // N*128 halves (25.6MB)
    float* bufH  = (float*)(ws + (size_t)N_NODES * HD / 2 + 64);  // N*128 f32
    float* h0    = bufH + (size_t)N_NODES * HD;          // N*16
    float* a_s   = h0   + (size_t)N_NODES * D_DIM;       // N*8
    float* a_d   = a_s  + (size_t)N_NODES * H_HEADS;     // N*8
    int*   deg     = (int*)(a_d + (size_t)N_NODES * H_HEADS);  // N
    int*   fill    = deg + N_NODES;                            // N
    int*   row_ptr = fill + N_NODES;                           // N+1
    int*   bsum    = row_ptr + (N_NODES + 1);                  // 256
    int*   boff    = bsum + SCAN_BLOCKS;                       // 256
    int*   bcount  = boff + SCAN_BLOCKS;                       // 16384
    int*   boffs   = bcount + 64 * SCAN_BLOCKS;                // 16384
    int*   perm    = boffs + 64 * SCAN_BLOCKS;                 // N
    int*   col     = perm + N_NODES;                           // E

    int edgeBlocks = (E_EDGES + 255) / 256;
    int aggrBlocks = (N_NODES + 15) / 16;

    // ----- CSR build (once; reused by both layers) -----
    hipMemsetAsync(deg, 0, (size_t)N_NODES * sizeof(int), stream);
    hipLaunchKernelGGL(hist_kernel, dim3(edgeBlocks), dim3(256), 0, stream, ei, deg);
    hipLaunchKernelGGL(block_sum_kernel, dim3(SCAN_BLOCKS), dim3(SCAN_T), 0, stream,
                       deg, bsum);
    hipLaunchKernelGGL(offset_scan_kernel, dim3(1), dim3(SCAN_BLOCKS), 0, stream,
                       bsum, boff);
    hipLaunchKernelGGL(row_ptr_kernel, dim3(SCAN_BLOCKS), dim3(SCAN_T), 0, stream,
                       deg, boff, row_ptr, fill);
    hipLaunchKernelGGL(scatter_kernel, dim3(edgeBlocks), dim3(256), 0, stream,
                       ei, fill, col);

    // ----- degree-bucket sort of dsts (contention-free) -----
    hipLaunchKernelGGL(bucket_hist_kernel, dim3(SCAN_BLOCKS), dim3(256), 0, stream,
                       deg, bcount);
    hipLaunchKernelGGL(bucket_scan_kernel, dim3(1), dim3(1024), 0, stream,
                       bcount, boffs);
    hipLaunchKernelGGL(bucket_scatter_kernel, dim3(SCAN_BLOCKS), dim3(256), 0, stream,
                       deg, boffs, perm);

    // ----- Embedding -----
    hipLaunchKernelGGL(embed_kernel, dim3(512), dim3(256), 0, stream,
                       x, W_emb, b_emb, h0);

    // ----- GAT layer 0 (K = 16) -----
    hipLaunchKernelGGL(transform_gemm_kernel<16>, dim3(2048), dim3(256), 0, stream,
                       h0, W0, as0, ad0, gH, a_s, a_d);
    hipLaunchKernelGGL(gat_aggr_csr_kernel<false>, dim3(aggrBlocks), dim3(256), 0, stream,
                       perm, row_ptr, col, a_s, a_d, gH, b0, bufH,
                       (const float*)nullptr, (const float*)nullptr,
                       (const float*)nullptr, (const float*)nullptr,
                       (const float*)nullptr, (const float*)nullptr,
                       (const float*)nullptr, (const float*)nullptr);

    // ----- GAT layer 1 (K = 128) + fused heads -----
    hipLaunchKernelGGL(transform_gemm_kernel<128>, dim3(1024), dim3(256), 0, stream,
                       bufH, W1, as1, ad1, gH, a_s, a_d);
    hipLaunchKernelGGL(gat_aggr_csr_kernel<true>, dim3(aggrBlocks), dim3(256), 0, stream,
                       perm, row_ptr, col, a_s, a_d, gH, b1, out,
                       Wy1, by1, Wy0, by0, Wc1, bc1, Wc2, bc2);
}

// Round 13
// 522.153 us; speedup vs baseline: 2.1281x; 1.0740x over previous
//
#include <hip/hip_runtime.h>
#include <hip/hip_fp16.h>
#include <math.h>

#define N_NODES 100000
#define E_EDGES 1600000
#define F_IN 128
#define D_DIM 16
#define H_HEADS 8
#define HD 128
#define NEG_SLOPE 0.2f

#define SCAN_BLOCKS 256
#define SCAN_T 256
#define SCAN_CH ((N_NODES + SCAN_BLOCKS - 1) / SCAN_BLOCKS)   // 391

#define NTILES ((N_NODES + 63) / 64)        // 1563 node-tiles of 64

// ---------------------------------------------------------------------------
// Embedding: h0[n, 0..15] = x[n, :] @ W_emb + b_emb   -> fp16
// ---------------------------------------------------------------------------
__global__ __launch_bounds__(256) void embed_kernel(
        const float* __restrict__ x, const float* __restrict__ W,
        const float* __restrict__ b, __half* __restrict__ h0) {
    __shared__ float Ws[F_IN * D_DIM];   // 8 KB
    __shared__ float bs[D_DIM];
    __shared__ float xs[16][F_IN + 1];
    int t = threadIdx.x;
    for (int i = t; i < F_IN * D_DIM; i += 256) Ws[i] = W[i];
    if (t < D_DIM) bs[t] = b[t];
    __syncthreads();
    for (int base = blockIdx.x * 16; base < N_NODES; base += gridDim.x * 16) {
        int cnt = min(16, N_NODES - base);
        __syncthreads();
        for (int i = t; i < cnt * F_IN; i += 256) {
            int nn = i >> 7, k = i & 127;
            xs[nn][k] = x[(size_t)(base + nn) * F_IN + k];
        }
        __syncthreads();
        int nn = t >> 4, c = t & 15;
        if (nn < cnt) {
            float a0 = 0.f, a1 = 0.f, a2 = 0.f, a3 = 0.f;
            #pragma unroll
            for (int k = 0; k < F_IN; k += 4) {
                a0 += xs[nn][k + 0] * Ws[(k + 0) * D_DIM + c];
                a1 += xs[nn][k + 1] * Ws[(k + 1) * D_DIM + c];
                a2 += xs[nn][k + 2] * Ws[(k + 2) * D_DIM + c];
                a3 += xs[nn][k + 3] * Ws[(k + 3) * D_DIM + c];
            }
            h0[(size_t)(base + nn) * D_DIM + c] =
                __float2half((a0 + a1) + (a2 + a3) + bs[c]);
        }
    }
}

// ---------------------------------------------------------------------------
// Precompute (1 block): u_s[h][c] = W0[c,:]|h-block . att_s0[h]; u_d likewise;
// W_fused[h*16+c][j] = sum_dp W0[c][h*16+dp] * W1[h*16+dp][j];
// bvec[j] = sum_k b0[k] * W1[k][j].
// ---------------------------------------------------------------------------
__global__ __launch_bounds__(256) void precompute_kernel(
        const float* __restrict__ W0, const float* __restrict__ W1,
        const float* __restrict__ as0, const float* __restrict__ ad0,
        const float* __restrict__ b0,
        float* __restrict__ W_fused, float* __restrict__ u_s,
        float* __restrict__ u_d, float* __restrict__ bvec) {
    int t = threadIdx.x;
    if (t < 128) {
        int h = t >> 4, c = t & 15;
        float ss = 0.f, sd = 0.f;
        for (int dp = 0; dp < 16; ++dp) {
            float w = W0[c * HD + h * 16 + dp];
            ss += w * as0[h * 16 + dp];
            sd += w * ad0[h * 16 + dp];
        }
        u_s[t] = ss; u_d[t] = sd;
        float bb = 0.f;
        for (int k = 0; k < HD; ++k) bb += b0[k] * W1[k * HD + t];
        bvec[t] = bb;
    }
    for (int idx = t; idx < HD * HD; idx += 256) {
        int i = idx >> 7, j = idx & 127;
        int h = i >> 4, c = i & 15;
        float s = 0.f;
        for (int dp = 0; dp < 16; ++dp)
            s += W0[c * HD + h * 16 + dp] * W1[(h * 16 + dp) * HD + j];
        W_fused[idx] = s;
    }
}

// ---------------------------------------------------------------------------
// Layer-0 attention dots: a_s0[n][h] = h0[n] . u_s[h], a_d0 likewise.
// Thread = (node, head): 8 threads per node.
// ---------------------------------------------------------------------------
__global__ __launch_bounds__(256) void attdot0_kernel(
        const __half* __restrict__ h0, const float* __restrict__ u_s,
        const float* __restrict__ u_d,
        float* __restrict__ a_s, float* __restrict__ a_d) {
    __shared__ float us[128], ud[128];
    int t = threadIdx.x;
    if (t < 128) { us[t] = u_s[t]; ud[t] = u_d[t]; }
    __syncthreads();
    int gidx = blockIdx.x * 256 + t;
    int n = gidx >> 3, h = gidx & 7;
    if (n >= N_NODES) return;
    const __half2* hp = (const __half2*)(h0 + (size_t)n * D_DIM);
    float ss = 0.f, sd = 0.f;
    #pragma unroll
    for (int c2 = 0; c2 < 8; ++c2) {
        float2 f = __half22float2(hp[c2]);
        ss += f.x * us[h * 16 + 2 * c2] + f.y * us[h * 16 + 2 * c2 + 1];
        sd += f.x * ud[h * 16 + 2 * c2] + f.y * ud[h * 16 + 2 * c2 + 1];
    }
    a_s[n * 8 + h] = ss;
    a_d[n * 8 + h] = sd;
}

// ---------------------------------------------------------------------------
// Node transform (layer 1) as register-tiled GEMM on fp16 input m:
// g1 = m @ W_fused + bvec (fp16 out), + attn dots from the biased values.
// ---------------------------------------------------------------------------
__global__ __launch_bounds__(256) void transform_fused_kernel(
        const __half* __restrict__ m, const float* __restrict__ W,
        const float* __restrict__ bvec,
        const float* __restrict__ att_s, const float* __restrict__ att_d,
        __half* __restrict__ g, float* __restrict__ a_src, float* __restrict__ a_dst) {
    __shared__ float Ws[128][64];        // 32 KB
    __shared__ float hs[64][128 + 4];    // 33 KB
    int t = threadIdx.x;
    int cq = t & 15;
    int nq = t >> 4;

    for (int item = blockIdx.x; item < NTILES * 2; item += gridDim.x) {
        int tile = item >> 1;
        int coff = (item & 1) << 6;
        int nbase = tile << 6;
        __syncthreads();
        for (int i = t; i < 128 * 64; i += 256)
            Ws[i >> 6][i & 63] = W[(size_t)(i >> 6) * HD + coff + (i & 63)];
        for (int i = t; i < (128 << 6); i += 256) {
            int r = i >> 7, k = i & 127;
            int n = nbase + r; if (n >= N_NODES) n = N_NODES - 1;
            hs[r][k] = __half2float(m[(size_t)n * HD + k]);
        }
        __syncthreads();

        float acc[4][4] = {{0.f}};
        #pragma unroll 2
        for (int k = 0; k < 128; k += 4) {
            float4 w0 = *(const float4*)&Ws[k + 0][cq << 2];
            float4 w1 = *(const float4*)&Ws[k + 1][cq << 2];
            float4 w2 = *(const float4*)&Ws[k + 2][cq << 2];
            float4 w3 = *(const float4*)&Ws[k + 3][cq << 2];
            #pragma unroll
            for (int j = 0; j < 4; ++j) {
                float4 hv = *(const float4*)&hs[(nq << 2) + j][k];
                acc[j][0] += hv.x * w0.x + hv.y * w1.x + hv.z * w2.x + hv.w * w3.x;
                acc[j][1] += hv.x * w0.y + hv.y * w1.y + hv.z * w2.y + hv.w * w3.y;
                acc[j][2] += hv.x * w0.z + hv.y * w1.z + hv.z * w2.z + hv.w * w3.z;
                acc[j][3] += hv.x * w0.w + hv.y * w1.w + hv.z * w2.w + hv.w * w3.w;
            }
        }

        int c0 = coff + (cq << 2);
        float bq0 = bvec[c0], bq1 = bvec[c0 + 1], bq2 = bvec[c0 + 2], bq3 = bvec[c0 + 3];
        float as0 = att_s[c0], as1 = att_s[c0 + 1], as2 = att_s[c0 + 2], as3 = att_s[c0 + 3];
        float ad0 = att_d[c0], ad1 = att_d[c0 + 1], ad2 = att_d[c0 + 2], ad3 = att_d[c0 + 3];
        int head = c0 >> 4;
        #pragma unroll
        for (int j = 0; j < 4; ++j) {
            int n = nbase + (nq << 2) + j;
            float g0 = acc[j][0] + bq0, g1v = acc[j][1] + bq1;
            float g2 = acc[j][2] + bq2, g3v = acc[j][3] + bq3;
            float ps = g0 * as0 + g1v * as1 + g2 * as2 + g3v * as3;
            float pd = g0 * ad0 + g1v * ad1 + g2 * ad2 + g3v * ad3;
            ps += __shfl_xor(ps, 1); ps += __shfl_xor(ps, 2);
            pd += __shfl_xor(pd, 1); pd += __shfl_xor(pd, 2);
            if (n < N_NODES) {
                union { __half2 h2[2]; uint2 u; } pk;
                pk.h2[0] = __floats2half2_rn(g0, g1v);
                pk.h2[1] = __floats2half2_rn(g2, g3v);
                *(uint2*)&g[(size_t)n * HD + c0] = pk.u;
                if ((cq & 3) == 0) {
                    a_src[(size_t)n * H_HEADS + head] = ps;
                    a_dst[(size_t)n * H_HEADS + head] = pd;
                }
            }
        }
    }
}

// ---------------------------------------------------------------------------
// CSR build: histogram -> 3-phase multi-block scan -> scatter.
// ---------------------------------------------------------------------------
__global__ __launch_bounds__(256) void hist_kernel(
        const int* __restrict__ ei, int* __restrict__ deg) {
    int e = blockIdx.x * 256 + threadIdx.x;
    if (e < E_EDGES) atomicAdd(&deg[ei[E_EDGES + e]], 1);
}

__global__ __launch_bounds__(SCAN_T) void block_sum_kernel(
        const int* __restrict__ deg, int* __restrict__ bsum) {
    int b = blockIdx.x, t = threadIdx.x;
    int lo = b * SCAN_CH, hi = min(lo + SCAN_CH, N_NODES);
    int s = 0;
    for (int i = lo + t; i < hi; i += SCAN_T) s += deg[i];
    #pragma unroll
    for (int m = 1; m < 64; m <<= 1) s += __shfl_xor(s, m);
    __shared__ int ws[SCAN_T / 64];
    if ((t & 63) == 0) ws[t >> 6] = s;
    __syncthreads();
    if (t == 0) {
        int tot = 0;
        #pragma unroll
        for (int w = 0; w < SCAN_T / 64; ++w) tot += ws[w];
        bsum[b] = tot;
    }
}

__global__ __launch_bounds__(SCAN_BLOCKS) void offset_scan_kernel(
        const int* __restrict__ bsum, int* __restrict__ boff) {
    __shared__ int tmp[SCAN_BLOCKS];
    int t = threadIdx.x;
    int v = bsum[t];
    tmp[t] = v;
    __syncthreads();
    int val = v;
    for (int off = 1; off < SCAN_BLOCKS; off <<= 1) {
        int o = (t >= off) ? tmp[t - off] : 0;
        __syncthreads();
        val += o;
        tmp[t] = val;
        __syncthreads();
    }
    boff[t] = val - v;    // exclusive
}

__global__ __launch_bounds__(SCAN_T) void row_ptr_kernel(
        const int* __restrict__ deg, const int* __restrict__ boff,
        int* __restrict__ row_ptr, int* __restrict__ fill) {
    int b = blockIdx.x, t = threadIdx.x;
    int lo = b * SCAN_CH, hi = min(lo + SCAN_CH, N_NODES);
    __shared__ int tmp[SCAN_T];
    __shared__ int carry;
    if (t == 0) carry = boff[b];
    __syncthreads();
    for (int base = lo; base < hi; base += SCAN_T) {
        int i = base + t;
        int v = (i < hi) ? deg[i] : 0;
        tmp[t] = v;
        __syncthreads();
        int val = v;
        for (int off = 1; off < SCAN_T; off <<= 1) {
            int o = (t >= off) ? tmp[t - off] : 0;
            __syncthreads();
            val += o;
            tmp[t] = val;
            __syncthreads();
        }
        int excl = val - v + carry;
        if (i < hi) { row_ptr[i] = excl; fill[i] = excl; }
        __syncthreads();
        if (t == SCAN_T - 1) carry = carry + val;
        __syncthreads();
    }
    if (b == SCAN_BLOCKS - 1 && t == 0) row_ptr[N_NODES] = carry;  // == E
}

__global__ __launch_bounds__(256) void scatter_kernel(
        const int* __restrict__ ei, int* __restrict__ fill,
        int* __restrict__ col) {
    int e = blockIdx.x * 256 + threadIdx.x;
    if (e < E_EDGES) {
        int d = ei[E_EDGES + e];
        int p = atomicAdd(&fill[d], 1);
        col[p] = ei[e];
    }
}

// ---------------------------------------------------------------------------
// Degree-bucket counting sort of dst nodes (contention-free, LDS atomics).
// ---------------------------------------------------------------------------
__global__ __launch_bounds__(256) void bucket_hist_kernel(
        const int* __restrict__ deg, int* __restrict__ bcount) {
    __shared__ int lh[64];
    int b = blockIdx.x, t = threadIdx.x;
    if (t < 64) lh[t] = 0;
    __syncthreads();
    int lo = b * SCAN_CH, hi = min(lo + SCAN_CH, N_NODES);
    for (int i = lo + t; i < hi; i += 256)
        atomicAdd(&lh[min(deg[i], 63)], 1);
    __syncthreads();
    if (t < 64) bcount[t * SCAN_BLOCKS + b] = lh[t];   // bucket-major
}

__global__ __launch_bounds__(1024) void bucket_scan_kernel(
        const int* __restrict__ bcount, int* __restrict__ boffs) {
    __shared__ int part[1024];
    int t = threadIdx.x;
    int base = t * 16;                       // 16384 = 64 buckets x 256 blocks
    int v[16]; int s = 0;
    #pragma unroll
    for (int k = 0; k < 16; ++k) { v[k] = bcount[base + k]; s += v[k]; }
    part[t] = s;
    __syncthreads();
    int val = s;
    for (int off = 1; off < 1024; off <<= 1) {
        int o = (t >= off) ? part[t - off] : 0;
        __syncthreads();
        val += o;
        part[t] = val;
        __syncthreads();
    }
    int run = val - s;
    #pragma unroll
    for (int k = 0; k < 16; ++k) { boffs[base + k] = run; run += v[k]; }
}

__global__ __launch_bounds__(256) void bucket_scatter_kernel(
        const int* __restrict__ deg, const int* __restrict__ boffs,
        int* __restrict__ perm) {
    __shared__ int lbase[64];
    int b = blockIdx.x, t = threadIdx.x;
    if (t < 64) lbase[t] = boffs[t * SCAN_BLOCKS + b];
    __syncthreads();
    int lo = b * SCAN_CH, hi = min(lo + SCAN_CH, N_NODES);
    for (int i = lo + t; i < hi; i += 256) {
        int p = atomicAdd(&lbase[min(deg[i], 63)], 1);   // LDS atomic only
        perm[p] = i;
    }
}

// ---------------------------------------------------------------------------
// Layer-0 aggregation: aggregate h0 DIRECTLY (transform commutes with the
// per-head weighted sum). Gathers 32 B fp16 h0 rows from a 3.2 MB table
// (L2-resident!) instead of 256 B g0 rows from 25.6 MB. Lane (within 16-lane
// group): cq = sub&3 -> channels 4cq..4cq+3, hp = sub>>2 -> heads 2hp,2hp+1.
// Output m[d][h*16+c] = sum_s alpha_s^h h0[s][c] (fp16, NO bias — folded into
// bvec downstream).
// ---------------------------------------------------------------------------
__global__ __launch_bounds__(256) void gat_aggr0_kernel(
        const int* __restrict__ perm,
        const int* __restrict__ row_ptr, const int* __restrict__ col,
        const float* __restrict__ a_src, const float* __restrict__ a_dst,
        const __half* __restrict__ h0, __half* __restrict__ m) {
    int wv = threadIdx.x >> 6, lane = threadIdx.x & 63;
    int grp = lane >> 4;
    int sub = lane & 15;
    int cq = sub & 3;
    int hp = sub >> 2;
    int slot = blockIdx.x * 16 + wv * 4 + grp;
    bool dvalid = slot < N_NODES;
    int d = perm[dvalid ? slot : N_NODES - 1];

    int i0 = row_ptr[d], end = row_ptr[d + 1];
    int deg = dvalid ? (end - i0) : 0;
    float2 ad = *(const float2*)(a_dst + (size_t)d * 8 + 2 * hp);

    float acc0[4], acc1[4];
    float den0, den1;
    {   // self loop
        float2 as = *(const float2*)(a_src + (size_t)d * 8 + 2 * hp);
        float l0 = as.x + ad.x; l0 = fmaxf(l0, NEG_SLOPE * l0);
        float l1 = as.y + ad.y; l1 = fmaxf(l1, NEG_SLOPE * l1);
        float w0 = __expf(l0), w1 = __expf(l1);
        uint2 hv = *(const uint2*)(h0 + (size_t)d * D_DIM + 4 * cq);
        float2 fa = __half22float2(*(__half2*)&hv.x);
        float2 fb = __half22float2(*(__half2*)&hv.y);
        acc0[0] = w0 * fa.x; acc0[1] = w0 * fa.y;
        acc0[2] = w0 * fb.x; acc0[3] = w0 * fb.y;
        acc1[0] = w1 * fa.x; acc1[1] = w1 * fa.y;
        acc1[2] = w1 * fb.x; acc1[3] = w1 * fb.y;
        den0 = w0; den1 = w1;
    }

    int md = deg;
    md = max(md, __shfl_xor(md, 16));
    md = max(md, __shfl_xor(md, 32));

    int colv = 0;
    #define EDGE_K(EL)                                                       \
    {                                                                        \
        int el_ = (EL);                                                      \
        int s = __shfl(colv, (grp << 4) | (el_ & 15));                       \
        float2 as = *(const float2*)(a_src + (size_t)s * 8 + 2 * hp);        \
        float l0 = as.x + ad.x; l0 = fmaxf(l0, NEG_SLOPE * l0);              \
        float l1 = as.y + ad.y; l1 = fmaxf(l1, NEG_SLOPE * l1);              \
        float w0 = (el_ < deg) ? __expf(l0) : 0.f;                           \
        float w1 = (el_ < deg) ? __expf(l1) : 0.f;                           \
        uint2 hv = *(const uint2*)(h0 + (size_t)s * D_DIM + 4 * cq);         \
        float2 fa = __half22float2(*(__half2*)&hv.x);                        \
        float2 fb = __half22float2(*(__half2*)&hv.y);                        \
        acc0[0] += w0 * fa.x; acc0[1] += w0 * fa.y;                          \
        acc0[2] += w0 * fb.x; acc0[3] += w0 * fb.y;                          \
        acc1[0] += w1 * fa.x; acc1[1] += w1 * fa.y;                          \
        acc1[2] += w1 * fb.x; acc1[3] += w1 * fb.y;                          \
        den0 += w0; den1 += w1;                                              \
    }

    for (int el = 0; el < md; el += 4) {
        if ((el & 15) == 0) {
            int ci = i0 + el + sub;
            ci = min(ci, end - 1);
            ci = max(ci, 0);
            colv = col[ci];
        }
        EDGE_K(el);
        EDGE_K(el + 1);
        EDGE_K(el + 2);
        EDGE_K(el + 3);
    }
    #undef EDGE_K

    float inv0 = 1.f / (den0 + 1e-16f);
    float inv1 = 1.f / (den1 + 1e-16f);
    if (dvalid) {
        union { __half2 h2[2]; uint2 u; } p0, p1;
        p0.h2[0] = __floats2half2_rn(acc0[0] * inv0, acc0[1] * inv0);
        p0.h2[1] = __floats2half2_rn(acc0[2] * inv0, acc0[3] * inv0);
        p1.h2[0] = __floats2half2_rn(acc1[0] * inv1, acc1[1] * inv1);
        p1.h2[1] = __floats2half2_rn(acc1[2] * inv1, acc1[3] * inv1);
        *(uint2*)(m + (size_t)d * HD + (2 * hp) * 16 + 4 * cq)       = p0.u;
        *(uint2*)(m + (size_t)d * HD + (2 * hp + 1) * 16 + 4 * cq)   = p1.u;
    }
}

// ---------------------------------------------------------------------------
// Layer-1 aggregation over CSR (unchanged from round 12) + fused heads.
// ---------------------------------------------------------------------------
__global__ __launch_bounds__(256) void gat_aggr1_kernel(
        const int* __restrict__ perm,
        const int* __restrict__ row_ptr, const int* __restrict__ col,
        const float* __restrict__ a_src, const float* __restrict__ a_dst,
        const __half* __restrict__ g, const float* __restrict__ bias,
        float* __restrict__ out,
        const float* __restrict__ Wy1, const float* __restrict__ by1,
        const float* __restrict__ Wy0, const float* __restrict__ by0,
        const float* __restrict__ Wc1, const float* __restrict__ bc1,
        const float* __restrict__ Wc2, const float* __restrict__ bc2) {
    int wv = threadIdx.x >> 6, lane = threadIdx.x & 63;
    int grp = lane >> 4;
    int sub = lane & 15;
    int hh  = sub >> 1;
    int slot = blockIdx.x * 16 + wv * 4 + grp;
    bool dvalid = slot < N_NODES;
    int d = perm[dvalid ? slot : N_NODES - 1];

    int i0 = row_ptr[d], end = row_ptr[d + 1];
    int deg = dvalid ? (end - i0) : 0;
    float ad = a_dst[d * 8 + hh];

    float acc[8];
    float den;
    {
        float a = a_src[d * 8 + hh] + ad;
        a = fmaxf(a, NEG_SLOPE * a);
        float w = __expf(a);
        uint4 rv = *(const uint4*)(g + (size_t)d * HD + (sub << 3));
        float2 f0 = __half22float2(*(__half2*)&rv.x);
        float2 f1 = __half22float2(*(__half2*)&rv.y);
        float2 f2 = __half22float2(*(__half2*)&rv.z);
        float2 f3 = __half22float2(*(__half2*)&rv.w);
        acc[0] = w * f0.x; acc[1] = w * f0.y;
        acc[2] = w * f1.x; acc[3] = w * f1.y;
        acc[4] = w * f2.x; acc[5] = w * f2.y;
        acc[6] = w * f3.x; acc[7] = w * f3.y;
        den = w;
    }

    int md = deg;
    md = max(md, __shfl_xor(md, 16));
    md = max(md, __shfl_xor(md, 32));

    int colv = 0;
    #define EDGE_K(EL)                                                       \
    {                                                                        \
        int el_ = (EL);                                                      \
        int s = __shfl(colv, (grp << 4) | (el_ & 15));                       \
        float a = a_src[s * 8 + hh] + ad;                                    \
        a = fmaxf(a, NEG_SLOPE * a);                                         \
        float w = (el_ < deg) ? __expf(a) : 0.f;                             \
        uint4 rv = *(const uint4*)(g + (size_t)s * HD + (sub << 3));         \
        float2 f0 = __half22float2(*(__half2*)&rv.x);                        \
        float2 f1 = __half22float2(*(__half2*)&rv.y);                        \
        float2 f2 = __half22float2(*(__half2*)&rv.z);                        \
        float2 f3 = __half22float2(*(__half2*)&rv.w);                        \
        acc[0] += w * f0.x; acc[1] += w * f0.y;                              \
        acc[2] += w * f1.x; acc[3] += w * f1.y;                              \
        acc[4] += w * f2.x; acc[5] += w * f2.y;                              \
        acc[6] += w * f3.x; acc[7] += w * f3.y;                              \
        den += w;                                                            \
    }

    for (int el = 0; el < md; el += 4) {
        if ((el & 15) == 0) {
            int ci = i0 + el + sub;
            ci = min(ci, end - 1);
            ci = max(ci, 0);
            colv = col[ci];
        }
        EDGE_K(el);
        EDGE_K(el + 1);
        EDGE_K(el + 2);
        EDGE_K(el + 3);
    }
    #undef EDGE_K

    float inv = 1.f / (den + 1e-16f);
    int c0 = sub << 3;
    float h[8];
    #pragma unroll
    for (int k = 0; k < 8; ++k) h[k] = acc[k] * inv + bias[c0 + k];

    // causal effect: width-16 reduction within the group
    float p = 0.f;
    #pragma unroll
    for (int k = 0; k < 8; ++k)
        p += h[k] * (Wy1[c0 + k] - Wy0[c0 + k]);
    p += __shfl_xor(p, 1); p += __shfl_xor(p, 2);
    p += __shfl_xor(p, 4); p += __shfl_xor(p, 8);
    // classifier MLP
    float acc2 = 0.f;
    #pragma unroll
    for (int j = 0; j < D_DIM; ++j) {
        float q = 0.f;
        #pragma unroll
        for (int k = 0; k < 8; ++k)
            q += h[k] * Wc1[(c0 + k) * D_DIM + j];
        q += __shfl_xor(q, 1); q += __shfl_xor(q, 2);
        q += __shfl_xor(q, 4); q += __shfl_xor(q, 8);
        float z = q + bc1[j];
        z = (z > 0.f) ? z : 0.f;
        acc2 += z * Wc2[j];
    }
    if (sub == 0 && dvalid) {
        out[d] = p + by1[0] - by0[0];
        out[N_NODES + d] = 1.f / (1.f + __expf(-(acc2 + bc2[0])));
    }
}

// ---------------------------------------------------------------------------
extern "C" void kernel_launch(void* const* d_in, const int* in_sizes, int n_in,
                              void* d_out, int out_size, void* d_ws, size_t ws_size,
                              hipStream_t stream) {
    const float* x     = (const float*)d_in[0];
    const int*   ei    = (const int*)  d_in[1];
    const float* W_emb = (const float*)d_in[2];
    const float* b_emb = (const float*)d_in[3];
    const float* W0    = (const float*)d_in[4];
    const float* as0   = (const float*)d_in[5];
    const float* ad0   = (const float*)d_in[6];
    const float* b0    = (const float*)d_in[7];
    const float* W1    = (const float*)d_in[8];
    const float* as1   = (const float*)d_in[9];
    const float* ad1   = (const float*)d_in[10];
    const float* b1    = (const float*)d_in[11];
    const float* Wy1   = (const float*)d_in[12];
    const float* by1   = (const float*)d_in[13];
    const float* Wy0   = (const float*)d_in[14];
    const float* by0   = (const float*)d_in[15];
    const float* Wc1   = (const float*)d_in[16];
    const float* bc1   = (const float*)d_in[17];
    const float* Wc2   = (const float*)d_in[18];
    const float* bc2   = (const float*)d_in[19];
    float* out = (float*)d_out;

    float* ws    = (float*)d_ws;
    __half* mH   = (__half*)ws;                              // N*128 half
    __half* gH   = (__half*)(ws + (size_t)N_NODES * 64);     // N*128 half
    __half* h0h  = (__half*)(ws + (size_t)N_NODES * 128);    // N*16 half
    float* a_s   = ws + (size_t)N_NODES * 128 + (size_t)N_NODES * 8;  // N*8
    float* a_d   = a_s + (size_t)N_NODES * 8;                // N*8
    float* Wf    = a_d + (size_t)N_NODES * 8;                // 16384
    float* u_s   = Wf + 16384;                               // 128
    float* u_d   = u_s + 128;                                // 128
    float* bvec  = u_d + 128;                                // 128
    int*   deg     = (int*)(bvec + 128);                     // N
    int*   fill    = deg + N_NODES;                          // N
    int*   row_ptr = fill + N_NODES;                         // N+1
    int*   bsum    = row_ptr + (N_NODES + 1);                // 256
    int*   boff    = bsum + SCAN_BLOCKS;                     // 256
    int*   bcount  = boff + SCAN_BLOCKS;                     // 16384
    int*   boffs   = bcount + 64 * SCAN_BLOCKS;              // 16384
    int*   perm    = boffs + 64 * SCAN_BLOCKS;               // N
    int*   col     = perm + N_NODES;                         // E

    int edgeBlocks = (E_EDGES + 255) / 256;
    int aggrBlocks = (N_NODES + 15) / 16;

    // ----- CSR build (once; reused by both layers) -----
    hipMemsetAsync(deg, 0, (size_t)N_NODES * sizeof(int), stream);
    hipLaunchKernelGGL(hist_kernel, dim3(edgeBlocks), dim3(256), 0, stream, ei, deg);
    hipLaunchKernelGGL(block_sum_kernel, dim3(SCAN_BLOCKS), dim3(SCAN_T), 0, stream,
                       deg, bsum);
    hipLaunchKernelGGL(offset_scan_kernel, dim3(1), dim3(SCAN_BLOCKS), 0, stream,
                       bsum, boff);
    hipLaunchKernelGGL(row_ptr_kernel, dim3(SCAN_BLOCKS), dim3(SCAN_T), 0, stream,
                       deg, boff, row_ptr, fill);
    hipLaunchKernelGGL(scatter_kernel, dim3(edgeBlocks), dim3(256), 0, stream,
                       ei, fill, col);

    // ----- degree-bucket sort of dsts (contention-free) -----
    hipLaunchKernelGGL(bucket_hist_kernel, dim3(SCAN_BLOCKS), dim3(256), 0, stream,
                       deg, bcount);
    hipLaunchKernelGGL(bucket_scan_kernel, dim3(1), dim3(1024), 0, stream,
                       bcount, boffs);
    hipLaunchKernelGGL(bucket_scatter_kernel, dim3(SCAN_BLOCKS), dim3(256), 0, stream,
                       deg, boffs, perm);

    // ----- Embedding (fp16 h0) + fused-weight precompute -----
    hipLaunchKernelGGL(embed_kernel, dim3(512), dim3(256), 0, stream,
                       x, W_emb, b_emb, h0h);
    hipLaunchKernelGGL(precompute_kernel, dim3(1), dim3(256), 0, stream,
                       W0, W1, as0, ad0, b0, Wf, u_s, u_d, bvec);

    // ----- Layer 0: attention dots from h0, aggregate h0 -> m -----
    hipLaunchKernelGGL(attdot0_kernel, dim3((N_NODES * 8 + 255) / 256), dim3(256),
                       0, stream, h0h, u_s, u_d, a_s, a_d);
    hipLaunchKernelGGL(gat_aggr0_kernel, dim3(aggrBlocks), dim3(256), 0, stream,
                       perm, row_ptr, col, a_s, a_d, h0h, mH);

    // ----- Layer 1: fused transform (m @ W_fused + bvec) + aggregation -----
    hipLaunchKernelGGL(transform_fused_kernel, dim3(1024), dim3(256), 0, stream,
                       mH, Wf, bvec, as1, ad1, gH, a_s, a_d);
    hipLaunchKernelGGL(gat_aggr1_kernel, dim3(aggrBlocks), dim3(256), 0, stream,
                       perm, row_ptr, col, a_s, a_d, gH, b1, out,
                       Wy1, by1, Wy0, by0, Wc1, bc1, Wc2, bc2);
}

// Round 14
// 456.876 us; speedup vs baseline: 2.4322x; 1.1429x over previous
//
#include <hip/hip_runtime.h>
#include <hip/hip_fp16.h>
#include <math.h>

#define N_NODES 100000
#define E_EDGES 1600000
#define F_IN 128
#define D_DIM 16
#define H_HEADS 8
#define HD 128
#define NEG_SLOPE 0.2f

#define SCAN_BLOCKS 256
#define SCAN_T 256
#define SCAN_CH ((N_NODES + SCAN_BLOCKS - 1) / SCAN_BLOCKS)   // 391

#define NTILES ((N_NODES + 63) / 64)        // 1563 node-tiles of 64

#define NB_E 196                            // edge buckets (512 dsts each)
#define EB 128                              // edge-partition blocks
#define CH_E ((E_EDGES + EB - 1) / EB)      // 12500 edges per block

// ---------------------------------------------------------------------------
// Embedding: h0[n, 0..15] = x[n, :] @ W_emb + b_emb   -> fp16
// ---------------------------------------------------------------------------
__global__ __launch_bounds__(256) void embed_kernel(
        const float* __restrict__ x, const float* __restrict__ W,
        const float* __restrict__ b, __half* __restrict__ h0) {
    __shared__ float Ws[F_IN * D_DIM];   // 8 KB
    __shared__ float bs[D_DIM];
    __shared__ float xs[16][F_IN + 1];
    int t = threadIdx.x;
    for (int i = t; i < F_IN * D_DIM; i += 256) Ws[i] = W[i];
    if (t < D_DIM) bs[t] = b[t];
    __syncthreads();
    for (int base = blockIdx.x * 16; base < N_NODES; base += gridDim.x * 16) {
        int cnt = min(16, N_NODES - base);
        __syncthreads();
        for (int i = t; i < cnt * F_IN; i += 256) {
            int nn = i >> 7, k = i & 127;
            xs[nn][k] = x[(size_t)(base + nn) * F_IN + k];
        }
        __syncthreads();
        int nn = t >> 4, c = t & 15;
        if (nn < cnt) {
            float a0 = 0.f, a1 = 0.f, a2 = 0.f, a3 = 0.f;
            #pragma unroll
            for (int k = 0; k < F_IN; k += 4) {
                a0 += xs[nn][k + 0] * Ws[(k + 0) * D_DIM + c];
                a1 += xs[nn][k + 1] * Ws[(k + 1) * D_DIM + c];
                a2 += xs[nn][k + 2] * Ws[(k + 2) * D_DIM + c];
                a3 += xs[nn][k + 3] * Ws[(k + 3) * D_DIM + c];
            }
            h0[(size_t)(base + nn) * D_DIM + c] =
                __float2half((a0 + a1) + (a2 + a3) + bs[c]);
        }
    }
}

// ---------------------------------------------------------------------------
// Precompute (1 block): u_s[h][c] = W0[c,:]|h-block . att_s0[h]; u_d likewise;
// W_fused[h*16+c][j] = sum_dp W0[c][h*16+dp] * W1[h*16+dp][j];
// bvec[j] = sum_k b0[k] * W1[k][j].
// ---------------------------------------------------------------------------
__global__ __launch_bounds__(256) void precompute_kernel(
        const float* __restrict__ W0, const float* __restrict__ W1,
        const float* __restrict__ as0, const float* __restrict__ ad0,
        const float* __restrict__ b0,
        float* __restrict__ W_fused, float* __restrict__ u_s,
        float* __restrict__ u_d, float* __restrict__ bvec) {
    int t = threadIdx.x;
    if (t < 128) {
        int h = t >> 4, c = t & 15;
        float ss = 0.f, sd = 0.f;
        for (int dp = 0; dp < 16; ++dp) {
            float w = W0[c * HD + h * 16 + dp];
            ss += w * as0[h * 16 + dp];
            sd += w * ad0[h * 16 + dp];
        }
        u_s[t] = ss; u_d[t] = sd;
        float bb = 0.f;
        for (int k = 0; k < HD; ++k) bb += b0[k] * W1[k * HD + t];
        bvec[t] = bb;
    }
    for (int idx = t; idx < HD * HD; idx += 256) {
        int i = idx >> 7, j = idx & 127;
        int h = i >> 4, c = i & 15;
        float s = 0.f;
        for (int dp = 0; dp < 16; ++dp)
            s += W0[c * HD + h * 16 + dp] * W1[(h * 16 + dp) * HD + j];
        W_fused[idx] = s;
    }
}

// ---------------------------------------------------------------------------
// Layer-0 attention dots: a_s0[n][h] = h0[n] . u_s[h], a_d0 likewise.
// ---------------------------------------------------------------------------
__global__ __launch_bounds__(256) void attdot0_kernel(
        const __half* __restrict__ h0, const float* __restrict__ u_s,
        const float* __restrict__ u_d,
        float* __restrict__ a_s, float* __restrict__ a_d) {
    __shared__ float us[128], ud[128];
    int t = threadIdx.x;
    if (t < 128) { us[t] = u_s[t]; ud[t] = u_d[t]; }
    __syncthreads();
    int gidx = blockIdx.x * 256 + t;
    int n = gidx >> 3, h = gidx & 7;
    if (n >= N_NODES) return;
    const __half2* hp = (const __half2*)(h0 + (size_t)n * D_DIM);
    float ss = 0.f, sd = 0.f;
    #pragma unroll
    for (int c2 = 0; c2 < 8; ++c2) {
        float2 f = __half22float2(hp[c2]);
        ss += f.x * us[h * 16 + 2 * c2] + f.y * us[h * 16 + 2 * c2 + 1];
        sd += f.x * ud[h * 16 + 2 * c2] + f.y * ud[h * 16 + 2 * c2 + 1];
    }
    a_s[n * 8 + h] = ss;
    a_d[n * 8 + h] = sd;
}

// ---------------------------------------------------------------------------
// Node transform (layer 1): g1 = m @ W_fused + bvec (fp16 out) + attn dots.
// ---------------------------------------------------------------------------
__global__ __launch_bounds__(256) void transform_fused_kernel(
        const __half* __restrict__ m, const float* __restrict__ W,
        const float* __restrict__ bvec,
        const float* __restrict__ att_s, const float* __restrict__ att_d,
        __half* __restrict__ g, float* __restrict__ a_src, float* __restrict__ a_dst) {
    __shared__ float Ws[128][64];        // 32 KB
    __shared__ float hs[64][128 + 4];    // 33 KB
    int t = threadIdx.x;
    int cq = t & 15;
    int nq = t >> 4;

    for (int item = blockIdx.x; item < NTILES * 2; item += gridDim.x) {
        int tile = item >> 1;
        int coff = (item & 1) << 6;
        int nbase = tile << 6;
        __syncthreads();
        for (int i = t; i < 128 * 64; i += 256)
            Ws[i >> 6][i & 63] = W[(size_t)(i >> 6) * HD + coff + (i & 63)];
        for (int i = t; i < (128 << 6); i += 256) {
            int r = i >> 7, k = i & 127;
            int n = nbase + r; if (n >= N_NODES) n = N_NODES - 1;
            hs[r][k] = __half2float(m[(size_t)n * HD + k]);
        }
        __syncthreads();

        float acc[4][4] = {{0.f}};
        #pragma unroll 2
        for (int k = 0; k < 128; k += 4) {
            float4 w0 = *(const float4*)&Ws[k + 0][cq << 2];
            float4 w1 = *(const float4*)&Ws[k + 1][cq << 2];
            float4 w2 = *(const float4*)&Ws[k + 2][cq << 2];
            float4 w3 = *(const float4*)&Ws[k + 3][cq << 2];
            #pragma unroll
            for (int j = 0; j < 4; ++j) {
                float4 hv = *(const float4*)&hs[(nq << 2) + j][k];
                acc[j][0] += hv.x * w0.x + hv.y * w1.x + hv.z * w2.x + hv.w * w3.x;
                acc[j][1] += hv.x * w0.y + hv.y * w1.y + hv.z * w2.y + hv.w * w3.y;
                acc[j][2] += hv.x * w0.z + hv.y * w1.z + hv.z * w2.z + hv.w * w3.z;
                acc[j][3] += hv.x * w0.w + hv.y * w1.w + hv.z * w2.w + hv.w * w3.w;
            }
        }

        int c0 = coff + (cq << 2);
        float bq0 = bvec[c0], bq1 = bvec[c0 + 1], bq2 = bvec[c0 + 2], bq3 = bvec[c0 + 3];
        float as0 = att_s[c0], as1 = att_s[c0 + 1], as2 = att_s[c0 + 2], as3 = att_s[c0 + 3];
        float ad0 = att_d[c0], ad1 = att_d[c0 + 1], ad2 = att_d[c0 + 2], ad3 = att_d[c0 + 3];
        int head = c0 >> 4;
        #pragma unroll
        for (int j = 0; j < 4; ++j) {
            int n = nbase + (nq << 2) + j;
            float g0 = acc[j][0] + bq0, g1v = acc[j][1] + bq1;
            float g2 = acc[j][2] + bq2, g3v = acc[j][3] + bq3;
            float ps = g0 * as0 + g1v * as1 + g2 * as2 + g3v * as3;
            float pd = g0 * ad0 + g1v * ad1 + g2 * ad2 + g3v * ad3;
            ps += __shfl_xor(ps, 1); ps += __shfl_xor(ps, 2);
            pd += __shfl_xor(pd, 1); pd += __shfl_xor(pd, 2);
            if (n < N_NODES) {
                union { __half2 h2[2]; uint2 u; } pk;
                pk.h2[0] = __floats2half2_rn(g0, g1v);
                pk.h2[1] = __floats2half2_rn(g2, g3v);
                *(uint2*)&g[(size_t)n * HD + c0] = pk.u;
                if ((cq & 3) == 0) {
                    a_src[(size_t)n * H_HEADS + head] = ps;
                    a_dst[(size_t)n * H_HEADS + head] = pd;
                }
            }
        }
    }
}

// ---------------------------------------------------------------------------
// CSR build: histogram -> 3-phase multi-block scan -> two-level scatter.
// ---------------------------------------------------------------------------
__global__ __launch_bounds__(256) void hist_kernel(
        const int* __restrict__ ei, int* __restrict__ deg) {
    int e = blockIdx.x * 256 + threadIdx.x;
    if (e < E_EDGES) atomicAdd(&deg[ei[E_EDGES + e]], 1);
}

__global__ __launch_bounds__(SCAN_T) void block_sum_kernel(
        const int* __restrict__ deg, int* __restrict__ bsum) {
    int b = blockIdx.x, t = threadIdx.x;
    int lo = b * SCAN_CH, hi = min(lo + SCAN_CH, N_NODES);
    int s = 0;
    for (int i = lo + t; i < hi; i += SCAN_T) s += deg[i];
    #pragma unroll
    for (int m = 1; m < 64; m <<= 1) s += __shfl_xor(s, m);
    __shared__ int ws[SCAN_T / 64];
    if ((t & 63) == 0) ws[t >> 6] = s;
    __syncthreads();
    if (t == 0) {
        int tot = 0;
        #pragma unroll
        for (int w = 0; w < SCAN_T / 64; ++w) tot += ws[w];
        bsum[b] = tot;
    }
}

__global__ __launch_bounds__(SCAN_BLOCKS) void offset_scan_kernel(
        const int* __restrict__ bsum, int* __restrict__ boff) {
    __shared__ int tmp[SCAN_BLOCKS];
    int t = threadIdx.x;
    int v = bsum[t];
    tmp[t] = v;
    __syncthreads();
    int val = v;
    for (int off = 1; off < SCAN_BLOCKS; off <<= 1) {
        int o = (t >= off) ? tmp[t - off] : 0;
        __syncthreads();
        val += o;
        tmp[t] = val;
        __syncthreads();
    }
    boff[t] = val - v;    // exclusive
}

__global__ __launch_bounds__(SCAN_T) void row_ptr_kernel(
        const int* __restrict__ deg, const int* __restrict__ boff,
        int* __restrict__ row_ptr) {
    int b = blockIdx.x, t = threadIdx.x;
    int lo = b * SCAN_CH, hi = min(lo + SCAN_CH, N_NODES);
    __shared__ int tmp[SCAN_T];
    __shared__ int carry;
    if (t == 0) carry = boff[b];
    __syncthreads();
    for (int base = lo; base < hi; base += SCAN_T) {
        int i = base + t;
        int v = (i < hi) ? deg[i] : 0;
        tmp[t] = v;
        __syncthreads();
        int val = v;
        for (int off = 1; off < SCAN_T; off <<= 1) {
            int o = (t >= off) ? tmp[t - off] : 0;
            __syncthreads();
            val += o;
            tmp[t] = val;
            __syncthreads();
        }
        int excl = val - v + carry;
        if (i < hi) row_ptr[i] = excl;
        __syncthreads();
        if (t == SCAN_T - 1) carry = carry + val;
        __syncthreads();
    }
    if (b == SCAN_BLOCKS - 1 && t == 0) row_ptr[N_NODES] = carry;  // == E
}

// ebfill[b] = start of bucket b's region in col/epack (= row_ptr[b*512])
__global__ __launch_bounds__(256) void ebfill_init_kernel(
        const int* __restrict__ row_ptr, int* __restrict__ ebfill) {
    int t = threadIdx.x;
    if (t < NB_E) ebfill[t] = row_ptr[t * 512];
}

// Level 1: partition edges into 196 dst-range buckets. Per-block LDS hist,
// ONE count-reservation atomic per (block,bucket), packed write
// (src<<9)|(dst&511). Writes land in per-(block,bucket) contiguous chunks.
__global__ __launch_bounds__(256) void edge_partition_kernel(
        const int* __restrict__ ei, int* __restrict__ ebfill,
        int* __restrict__ epack) {
    __shared__ int lh[NB_E];
    __shared__ int lbase[NB_E];
    int b = blockIdx.x, t = threadIdx.x;
    int lo = b * CH_E, hi = min(lo + CH_E, E_EDGES);
    for (int i = t; i < NB_E; i += 256) lh[i] = 0;
    __syncthreads();
    for (int e = lo + t; e < hi; e += 256)
        atomicAdd(&lh[ei[E_EDGES + e] >> 9], 1);
    __syncthreads();
    if (t < NB_E) lbase[t] = atomicAdd(&ebfill[t], lh[t]);
    __syncthreads();
    for (int e = lo + t; e < hi; e += 256) {
        int s = ei[e], d = ei[E_EDGES + e];
        int p = atomicAdd(&lbase[d >> 9], 1);       // LDS atomic
        epack[p] = (s << 9) | (d & 511);
    }
}

// Level 2: one block per bucket. LDS fill counters initialized from row_ptr;
// all col writes land in the bucket's 32 KB L2-resident region -> lines
// fill densely before eviction (write-back ~= col size, not 64B/edge).
__global__ __launch_bounds__(256) void bucket_col_kernel(
        const int* __restrict__ row_ptr, const int* __restrict__ epack,
        int* __restrict__ col) {
    __shared__ int lfill[512];
    int b = blockIdx.x, t = threadIdx.x;
    int nb0 = b * 512;
    for (int k = t; k < 512; k += 256)
        lfill[k] = row_ptr[min(nb0 + k, N_NODES)];
    __syncthreads();
    int lo = row_ptr[nb0];
    int hi = row_ptr[min(nb0 + 512, N_NODES)];
    for (int i = lo + t; i < hi; i += 256) {
        int v = epack[i];
        int p = atomicAdd(&lfill[v & 511], 1);      // LDS atomic
        col[p] = ((unsigned)v) >> 9;
    }
}

// ---------------------------------------------------------------------------
// Degree-bucket counting sort of dst nodes (contention-free, LDS atomics).
// ---------------------------------------------------------------------------
__global__ __launch_bounds__(256) void bucket_hist_kernel(
        const int* __restrict__ deg, int* __restrict__ bcount) {
    __shared__ int lh[64];
    int b = blockIdx.x, t = threadIdx.x;
    if (t < 64) lh[t] = 0;
    __syncthreads();
    int lo = b * SCAN_CH, hi = min(lo + SCAN_CH, N_NODES);
    for (int i = lo + t; i < hi; i += 256)
        atomicAdd(&lh[min(deg[i], 63)], 1);
    __syncthreads();
    if (t < 64) bcount[t * SCAN_BLOCKS + b] = lh[t];   // bucket-major
}

__global__ __launch_bounds__(1024) void bucket_scan_kernel(
        const int* __restrict__ bcount, int* __restrict__ boffs) {
    __shared__ int part[1024];
    int t = threadIdx.x;
    int base = t * 16;                       // 16384 = 64 buckets x 256 blocks
    int v[16]; int s = 0;
    #pragma unroll
    for (int k = 0; k < 16; ++k) { v[k] = bcount[base + k]; s += v[k]; }
    part[t] = s;
    __syncthreads();
    int val = s;
    for (int off = 1; off < 1024; off <<= 1) {
        int o = (t >= off) ? part[t - off] : 0;
        __syncthreads();
        val += o;
        part[t] = val;
        __syncthreads();
    }
    int run = val - s;
    #pragma unroll
    for (int k = 0; k < 16; ++k) { boffs[base + k] = run; run += v[k]; }
}

__global__ __launch_bounds__(256) void bucket_scatter_kernel(
        const int* __restrict__ deg, const int* __restrict__ boffs,
        int* __restrict__ perm) {
    __shared__ int lbase[64];
    int b = blockIdx.x, t = threadIdx.x;
    if (t < 64) lbase[t] = boffs[t * SCAN_BLOCKS + b];
    __syncthreads();
    int lo = b * SCAN_CH, hi = min(lo + SCAN_CH, N_NODES);
    for (int i = lo + t; i < hi; i += 256) {
        int p = atomicAdd(&lbase[min(deg[i], 63)], 1);   // LDS atomic only
        perm[p] = i;
    }
}

// ---------------------------------------------------------------------------
// Layer-0 aggregation: aggregate h0 DIRECTLY (32 B rows, 3.2 MB L2-resident).
// ---------------------------------------------------------------------------
__global__ __launch_bounds__(256) void gat_aggr0_kernel(
        const int* __restrict__ perm,
        const int* __restrict__ row_ptr, const int* __restrict__ col,
        const float* __restrict__ a_src, const float* __restrict__ a_dst,
        const __half* __restrict__ h0, __half* __restrict__ m) {
    int wv = threadIdx.x >> 6, lane = threadIdx.x & 63;
    int grp = lane >> 4;
    int sub = lane & 15;
    int cq = sub & 3;
    int hp = sub >> 2;
    int slot = blockIdx.x * 16 + wv * 4 + grp;
    bool dvalid = slot < N_NODES;
    int d = perm[dvalid ? slot : N_NODES - 1];

    int i0 = row_ptr[d], end = row_ptr[d + 1];
    int deg = dvalid ? (end - i0) : 0;
    float2 ad = *(const float2*)(a_dst + (size_t)d * 8 + 2 * hp);

    float acc0[4], acc1[4];
    float den0, den1;
    {   // self loop
        float2 as = *(const float2*)(a_src + (size_t)d * 8 + 2 * hp);
        float l0 = as.x + ad.x; l0 = fmaxf(l0, NEG_SLOPE * l0);
        float l1 = as.y + ad.y; l1 = fmaxf(l1, NEG_SLOPE * l1);
        float w0 = __expf(l0), w1 = __expf(l1);
        uint2 hv = *(const uint2*)(h0 + (size_t)d * D_DIM + 4 * cq);
        float2 fa = __half22float2(*(__half2*)&hv.x);
        float2 fb = __half22float2(*(__half2*)&hv.y);
        acc0[0] = w0 * fa.x; acc0[1] = w0 * fa.y;
        acc0[2] = w0 * fb.x; acc0[3] = w0 * fb.y;
        acc1[0] = w1 * fa.x; acc1[1] = w1 * fa.y;
        acc1[2] = w1 * fb.x; acc1[3] = w1 * fb.y;
        den0 = w0; den1 = w1;
    }

    int md = deg;
    md = max(md, __shfl_xor(md, 16));
    md = max(md, __shfl_xor(md, 32));

    int colv = 0;
    #define EDGE_K(EL)                                                       \
    {                                                                        \
        int el_ = (EL);                                                      \
        int s = __shfl(colv, (grp << 4) | (el_ & 15));                       \
        float2 as = *(const float2*)(a_src + (size_t)s * 8 + 2 * hp);        \
        float l0 = as.x + ad.x; l0 = fmaxf(l0, NEG_SLOPE * l0);              \
        float l1 = as.y + ad.y; l1 = fmaxf(l1, NEG_SLOPE * l1);              \
        float w0 = (el_ < deg) ? __expf(l0) : 0.f;                           \
        float w1 = (el_ < deg) ? __expf(l1) : 0.f;                           \
        uint2 hv = *(const uint2*)(h0 + (size_t)s * D_DIM + 4 * cq);         \
        float2 fa = __half22float2(*(__half2*)&hv.x);                        \
        float2 fb = __half22float2(*(__half2*)&hv.y);                        \
        acc0[0] += w0 * fa.x; acc0[1] += w0 * fa.y;                          \
        acc0[2] += w0 * fb.x; acc0[3] += w0 * fb.y;                          \
        acc1[0] += w1 * fa.x; acc1[1] += w1 * fa.y;                          \
        acc1[2] += w1 * fb.x; acc1[3] += w1 * fb.y;                          \
        den0 += w0; den1 += w1;                                              \
    }

    for (int el = 0; el < md; el += 4) {
        if ((el & 15) == 0) {
            int ci = i0 + el + sub;
            ci = min(ci, end - 1);
            ci = max(ci, 0);
            colv = col[ci];
        }
        EDGE_K(el);
        EDGE_K(el + 1);
        EDGE_K(el + 2);
        EDGE_K(el + 3);
    }
    #undef EDGE_K

    float inv0 = 1.f / (den0 + 1e-16f);
    float inv1 = 1.f / (den1 + 1e-16f);
    if (dvalid) {
        union { __half2 h2[2]; uint2 u; } p0, p1;
        p0.h2[0] = __floats2half2_rn(acc0[0] * inv0, acc0[1] * inv0);
        p0.h2[1] = __floats2half2_rn(acc0[2] * inv0, acc0[3] * inv0);
        p1.h2[0] = __floats2half2_rn(acc1[0] * inv1, acc1[1] * inv1);
        p1.h2[1] = __floats2half2_rn(acc1[2] * inv1, acc1[3] * inv1);
        *(uint2*)(m + (size_t)d * HD + (2 * hp) * 16 + 4 * cq)       = p0.u;
        *(uint2*)(m + (size_t)d * HD + (2 * hp + 1) * 16 + 4 * cq)   = p1.u;
    }
}

// ---------------------------------------------------------------------------
// Layer-1 aggregation over CSR + fused heads.
// ---------------------------------------------------------------------------
__global__ __launch_bounds__(256) void gat_aggr1_kernel(
        const int* __restrict__ perm,
        const int* __restrict__ row_ptr, const int* __restrict__ col,
        const float* __restrict__ a_src, const float* __restrict__ a_dst,
        const __half* __restrict__ g, const float* __restrict__ bias,
        float* __restrict__ out,
        const float* __restrict__ Wy1, const float* __restrict__ by1,
        const float* __restrict__ Wy0, const float* __restrict__ by0,
        const float* __restrict__ Wc1, const float* __restrict__ bc1,
        const float* __restrict__ Wc2, const float* __restrict__ bc2) {
    int wv = threadIdx.x >> 6, lane = threadIdx.x & 63;
    int grp = lane >> 4;
    int sub = lane & 15;
    int hh  = sub >> 1;
    int slot = blockIdx.x * 16 + wv * 4 + grp;
    bool dvalid = slot < N_NODES;
    int d = perm[dvalid ? slot : N_NODES - 1];

    int i0 = row_ptr[d], end = row_ptr[d + 1];
    int deg = dvalid ? (end - i0) : 0;
    float ad = a_dst[d * 8 + hh];

    float acc[8];
    float den;
    {
        float a = a_src[d * 8 + hh] + ad;
        a = fmaxf(a, NEG_SLOPE * a);
        float w = __expf(a);
        uint4 rv = *(const uint4*)(g + (size_t)d * HD + (sub << 3));
        float2 f0 = __half22float2(*(__half2*)&rv.x);
        float2 f1 = __half22float2(*(__half2*)&rv.y);
        float2 f2 = __half22float2(*(__half2*)&rv.z);
        float2 f3 = __half22float2(*(__half2*)&rv.w);
        acc[0] = w * f0.x; acc[1] = w * f0.y;
        acc[2] = w * f1.x; acc[3] = w * f1.y;
        acc[4] = w * f2.x; acc[5] = w * f2.y;
        acc[6] = w * f3.x; acc[7] = w * f3.y;
        den = w;
    }

    int md = deg;
    md = max(md, __shfl_xor(md, 16));
    md = max(md, __shfl_xor(md, 32));

    int colv = 0;
    #define EDGE_K(EL)                                                       \
    {                                                                        \
        int el_ = (EL);                                                      \
        int s = __shfl(colv, (grp << 4) | (el_ & 15));                       \
        float a = a_src[s * 8 + hh] + ad;                                    \
        a = fmaxf(a, NEG_SLOPE * a);                                         \
        float w = (el_ < deg) ? __expf(a) : 0.f;                             \
        uint4 rv = *(const uint4*)(g + (size_t)s * HD + (sub << 3));         \
        float2 f0 = __half22float2(*(__half2*)&rv.x);                        \
        float2 f1 = __half22float2(*(__half2*)&rv.y);                        \
        float2 f2 = __half22float2(*(__half2*)&rv.z);                        \
        float2 f3 = __half22float2(*(__half2*)&rv.w);                        \
        acc[0] += w * f0.x; acc[1] += w * f0.y;                              \
        acc[2] += w * f1.x; acc[3] += w * f1.y;                              \
        acc[4] += w * f2.x; acc[5] += w * f2.y;                              \
        acc[6] += w * f3.x; acc[7] += w * f3.y;                              \
        den += w;                                                            \
    }

    for (int el = 0; el < md; el += 4) {
        if ((el & 15) == 0) {
            int ci = i0 + el + sub;
            ci = min(ci, end - 1);
            ci = max(ci, 0);
            colv = col[ci];
        }
        EDGE_K(el);
        EDGE_K(el + 1);
        EDGE_K(el + 2);
        EDGE_K(el + 3);
    }
    #undef EDGE_K

    float inv = 1.f / (den + 1e-16f);
    int c0 = sub << 3;
    float h[8];
    #pragma unroll
    for (int k = 0; k < 8; ++k) h[k] = acc[k] * inv + bias[c0 + k];

    // causal effect: width-16 reduction within the group
    float p = 0.f;
    #pragma unroll
    for (int k = 0; k < 8; ++k)
        p += h[k] * (Wy1[c0 + k] - Wy0[c0 + k]);
    p += __shfl_xor(p, 1); p += __shfl_xor(p, 2);
    p += __shfl_xor(p, 4); p += __shfl_xor(p, 8);
    // classifier MLP
    float acc2 = 0.f;
    #pragma unroll
    for (int j = 0; j < D_DIM; ++j) {
        float q = 0.f;
        #pragma unroll
        for (int k = 0; k < 8; ++k)
            q += h[k] * Wc1[(c0 + k) * D_DIM + j];
        q += __shfl_xor(q, 1); q += __shfl_xor(q, 2);
        q += __shfl_xor(q, 4); q += __shfl_xor(q, 8);
        float z = q + bc1[j];
        z = (z > 0.f) ? z : 0.f;
        acc2 += z * Wc2[j];
    }
    if (sub == 0 && dvalid) {
        out[d] = p + by1[0] - by0[0];
        out[N_NODES + d] = 1.f / (1.f + __expf(-(acc2 + bc2[0])));
    }
}

// ---------------------------------------------------------------------------
extern "C" void kernel_launch(void* const* d_in, const int* in_sizes, int n_in,
                              void* d_out, int out_size, void* d_ws, size_t ws_size,
                              hipStream_t stream) {
    const float* x     = (const float*)d_in[0];
    const int*   ei    = (const int*)  d_in[1];
    const float* W_emb = (const float*)d_in[2];
    const float* b_emb = (const float*)d_in[3];
    const float* W0    = (const float*)d_in[4];
    const float* as0   = (const float*)d_in[5];
    const float* ad0   = (const float*)d_in[6];
    const float* b0    = (const float*)d_in[7];
    const float* W1    = (const float*)d_in[8];
    const float* as1   = (const float*)d_in[9];
    const float* ad1   = (const float*)d_in[10];
    const float* b1    = (const float*)d_in[11];
    const float* Wy1   = (const float*)d_in[12];
    const float* by1   = (const float*)d_in[13];
    const float* Wy0   = (const float*)d_in[14];
    const float* by0   = (const float*)d_in[15];
    const float* Wc1   = (const float*)d_in[16];
    const float* bc1   = (const float*)d_in[17];
    const float* Wc2   = (const float*)d_in[18];
    const float* bc2   = (const float*)d_in[19];
    float* out = (float*)d_out;

    float* ws    = (float*)d_ws;
    __half* mH   = (__half*)ws;                              // N*128 half
    __half* gH   = (__half*)(ws + (size_t)N_NODES * 64);     // N*128 half
    __half* h0h  = (__half*)(ws + (size_t)N_NODES * 128);    // N*16 half
    float* a_s   = ws + (size_t)N_NODES * 136;               // N*8
    float* a_d   = a_s + (size_t)N_NODES * 8;                // N*8
    float* Wf    = a_d + (size_t)N_NODES * 8;                // 16384
    float* u_s   = Wf + 16384;                               // 128
    float* u_d   = u_s + 128;                                // 128
    float* bvec  = u_d + 128;                                // 128
    int*   deg     = (int*)(bvec + 128);                     // N
    int*   row_ptr = deg + N_NODES;                          // N+1
    int*   bsum    = row_ptr + (N_NODES + 1);                // 256
    int*   boff    = bsum + SCAN_BLOCKS;                     // 256
    int*   bcount  = boff + SCAN_BLOCKS;                     // 16384
    int*   boffs   = bcount + 64 * SCAN_BLOCKS;              // 16384
    int*   perm    = boffs + 64 * SCAN_BLOCKS;               // N
    int*   col     = perm + N_NODES;                         // E
    int*   epack   = col + E_EDGES;                          // E
    int*   ebfill  = epack + E_EDGES;                        // 256

    int edgeBlocks = (E_EDGES + 255) / 256;
    int aggrBlocks = (N_NODES + 15) / 16;

    // ----- degree histogram + row_ptr -----
    hipMemsetAsync(deg, 0, (size_t)N_NODES * sizeof(int), stream);
    hipLaunchKernelGGL(hist_kernel, dim3(edgeBlocks), dim3(256), 0, stream, ei, deg);
    hipLaunchKernelGGL(block_sum_kernel, dim3(SCAN_BLOCKS), dim3(SCAN_T), 0, stream,
                       deg, bsum);
    hipLaunchKernelGGL(offset_scan_kernel, dim3(1), dim3(SCAN_BLOCKS), 0, stream,
                       bsum, boff);
    hipLaunchKernelGGL(row_ptr_kernel, dim3(SCAN_BLOCKS), dim3(SCAN_T), 0, stream,
                       deg, boff, row_ptr);

    // ----- two-level write-local col scatter -----
    hipLaunchKernelGGL(ebfill_init_kernel, dim3(1), dim3(256), 0, stream,
                       row_ptr, ebfill);
    hipLaunchKernelGGL(edge_partition_kernel, dim3(EB), dim3(256), 0, stream,
                       ei, ebfill, epack);
    hipLaunchKernelGGL(bucket_col_kernel, dim3(NB_E), dim3(256), 0, stream,
                       row_ptr, epack, col);

    // ----- degree-bucket sort of dsts (contention-free) -----
    hipLaunchKernelGGL(bucket_hist_kernel, dim3(SCAN_BLOCKS), dim3(256), 0, stream,
                       deg, bcount);
    hipLaunchKernelGGL(bucket_scan_kernel, dim3(1), dim3(1024), 0, stream,
                       bcount, boffs);
    hipLaunchKernelGGL(bucket_scatter_kernel, dim3(SCAN_BLOCKS), dim3(256), 0, stream,
                       deg, boffs, perm);

    // ----- Embedding (fp16 h0) + fused-weight precompute -----
    hipLaunchKernelGGL(embed_kernel, dim3(512), dim3(256), 0, stream,
                       x, W_emb, b_emb, h0h);
    hipLaunchKernelGGL(precompute_kernel, dim3(1), dim3(256), 0, stream,
                       W0, W1, as0, ad0, b0, Wf, u_s, u_d, bvec);

    // ----- Layer 0: attention dots from h0, aggregate h0 -> m -----
    hipLaunchKernelGGL(attdot0_kernel, dim3((N_NODES * 8 + 255) / 256), dim3(256),
                       0, stream, h0h, u_s, u_d, a_s, a_d);
    hipLaunchKernelGGL(gat_aggr0_kernel, dim3(aggrBlocks), dim3(256), 0, stream,
                       perm, row_ptr, col, a_s, a_d, h0h, mH);

    // ----- Layer 1: fused transform (m @ W_fused + bvec) + aggregation -----
    hipLaunchKernelGGL(transform_fused_kernel, dim3(1024), dim3(256), 0, stream,
                       mH, Wf, bvec, as1, ad1, gH, a_s, a_d);
    hipLaunchKernelGGL(gat_aggr1_kernel, dim3(aggrBlocks), dim3(256), 0, stream,
                       perm, row_ptr, col, a_s, a_d, gH, b1, out,
                       Wy1, by1, Wy0, by0, Wc1, bc1, Wc2, bc2);
}

// Round 15
// 415.891 us; speedup vs baseline: 2.6718x; 1.0985x over previous
//
#include <hip/hip_runtime.h>
#include <hip/hip_fp16.h>
#include <math.h>

#define N_NODES 100000
#define E_EDGES 1600000
#define F_IN 128
#define D_DIM 16
#define H_HEADS 8
#define HD 128
#define NEG_SLOPE 0.2f

#define SCAN_BLOCKS 256
#define SCAN_CH ((N_NODES + SCAN_BLOCKS - 1) / SCAN_BLOCKS)   // 391

#define NTILES ((N_NODES + 63) / 64)        // 1563 node-tiles of 64

#define NB_E 196                            // edge buckets (512 dsts each)
#define EB 128                              // edge-partition blocks
#define CH_E ((E_EDGES + EB - 1) / EB)      // 12500 edges per block
#define NBB (NB_E * EB)                     // 25088 (bucket, block) cells

// ---------------------------------------------------------------------------
// Embedding: h0[n, 0..15] = x[n, :] @ W_emb + b_emb   -> fp16
// ---------------------------------------------------------------------------
__global__ __launch_bounds__(256) void embed_kernel(
        const float* __restrict__ x, const float* __restrict__ W,
        const float* __restrict__ b, __half* __restrict__ h0) {
    __shared__ float Ws[F_IN * D_DIM];   // 8 KB
    __shared__ float bs[D_DIM];
    __shared__ float xs[16][F_IN + 1];
    int t = threadIdx.x;
    for (int i = t; i < F_IN * D_DIM; i += 256) Ws[i] = W[i];
    if (t < D_DIM) bs[t] = b[t];
    __syncthreads();
    for (int base = blockIdx.x * 16; base < N_NODES; base += gridDim.x * 16) {
        int cnt = min(16, N_NODES - base);
        __syncthreads();
        for (int i = t; i < cnt * F_IN; i += 256) {
            int nn = i >> 7, k = i & 127;
            xs[nn][k] = x[(size_t)(base + nn) * F_IN + k];
        }
        __syncthreads();
        int nn = t >> 4, c = t & 15;
        if (nn < cnt) {
            float a0 = 0.f, a1 = 0.f, a2 = 0.f, a3 = 0.f;
            #pragma unroll
            for (int k = 0; k < F_IN; k += 4) {
                a0 += xs[nn][k + 0] * Ws[(k + 0) * D_DIM + c];
                a1 += xs[nn][k + 1] * Ws[(k + 1) * D_DIM + c];
                a2 += xs[nn][k + 2] * Ws[(k + 2) * D_DIM + c];
                a3 += xs[nn][k + 3] * Ws[(k + 3) * D_DIM + c];
            }
            h0[(size_t)(base + nn) * D_DIM + c] =
                __float2half((a0 + a1) + (a2 + a3) + bs[c]);
        }
    }
}

// ---------------------------------------------------------------------------
// Precompute (1 block): u_s/u_d (layer-0 attn vectors in h0 space),
// W_fused = BD(W0) @ W1, bvec = b0 @ W1.
// ---------------------------------------------------------------------------
__global__ __launch_bounds__(256) void precompute_kernel(
        const float* __restrict__ W0, const float* __restrict__ W1,
        const float* __restrict__ as0, const float* __restrict__ ad0,
        const float* __restrict__ b0,
        float* __restrict__ W_fused, float* __restrict__ u_s,
        float* __restrict__ u_d, float* __restrict__ bvec) {
    int t = threadIdx.x;
    if (t < 128) {
        int h = t >> 4, c = t & 15;
        float ss = 0.f, sd = 0.f;
        for (int dp = 0; dp < 16; ++dp) {
            float w = W0[c * HD + h * 16 + dp];
            ss += w * as0[h * 16 + dp];
            sd += w * ad0[h * 16 + dp];
        }
        u_s[t] = ss; u_d[t] = sd;
        float bb = 0.f;
        for (int k = 0; k < HD; ++k) bb += b0[k] * W1[k * HD + t];
        bvec[t] = bb;
    }
    for (int idx = t; idx < HD * HD; idx += 256) {
        int i = idx >> 7, j = idx & 127;
        int h = i >> 4, c = i & 15;
        float s = 0.f;
        for (int dp = 0; dp < 16; ++dp)
            s += W0[c * HD + h * 16 + dp] * W1[(h * 16 + dp) * HD + j];
        W_fused[idx] = s;
    }
}

// ---------------------------------------------------------------------------
// Layer-0 attention dots: a_s0[n][h] = h0[n] . u_s[h], a_d0 likewise.
// ---------------------------------------------------------------------------
__global__ __launch_bounds__(256) void attdot0_kernel(
        const __half* __restrict__ h0, const float* __restrict__ u_s,
        const float* __restrict__ u_d,
        float* __restrict__ a_s, float* __restrict__ a_d) {
    __shared__ float us[128], ud[128];
    int t = threadIdx.x;
    if (t < 128) { us[t] = u_s[t]; ud[t] = u_d[t]; }
    __syncthreads();
    int gidx = blockIdx.x * 256 + t;
    int n = gidx >> 3, h = gidx & 7;
    if (n >= N_NODES) return;
    const __half2* hp = (const __half2*)(h0 + (size_t)n * D_DIM);
    float ss = 0.f, sd = 0.f;
    #pragma unroll
    for (int c2 = 0; c2 < 8; ++c2) {
        float2 f = __half22float2(hp[c2]);
        ss += f.x * us[h * 16 + 2 * c2] + f.y * us[h * 16 + 2 * c2 + 1];
        sd += f.x * ud[h * 16 + 2 * c2] + f.y * ud[h * 16 + 2 * c2 + 1];
    }
    a_s[n * 8 + h] = ss;
    a_d[n * 8 + h] = sd;
}

// ---------------------------------------------------------------------------
// Node transform (layer 1): g1 = m @ W_fused + bvec (fp16 out) + attn dots.
// ---------------------------------------------------------------------------
__global__ __launch_bounds__(256) void transform_fused_kernel(
        const __half* __restrict__ m, const float* __restrict__ W,
        const float* __restrict__ bvec,
        const float* __restrict__ att_s, const float* __restrict__ att_d,
        __half* __restrict__ g, float* __restrict__ a_src, float* __restrict__ a_dst) {
    __shared__ float Ws[128][64];        // 32 KB
    __shared__ float hs[64][128 + 4];    // 33 KB
    int t = threadIdx.x;
    int cq = t & 15;
    int nq = t >> 4;

    for (int item = blockIdx.x; item < NTILES * 2; item += gridDim.x) {
        int tile = item >> 1;
        int coff = (item & 1) << 6;
        int nbase = tile << 6;
        __syncthreads();
        for (int i = t; i < 128 * 64; i += 256)
            Ws[i >> 6][i & 63] = W[(size_t)(i >> 6) * HD + coff + (i & 63)];
        for (int i = t; i < (128 << 6); i += 256) {
            int r = i >> 7, k = i & 127;
            int n = nbase + r; if (n >= N_NODES) n = N_NODES - 1;
            hs[r][k] = __half2float(m[(size_t)n * HD + k]);
        }
        __syncthreads();

        float acc[4][4] = {{0.f}};
        #pragma unroll 2
        for (int k = 0; k < 128; k += 4) {
            float4 w0 = *(const float4*)&Ws[k + 0][cq << 2];
            float4 w1 = *(const float4*)&Ws[k + 1][cq << 2];
            float4 w2 = *(const float4*)&Ws[k + 2][cq << 2];
            float4 w3 = *(const float4*)&Ws[k + 3][cq << 2];
            #pragma unroll
            for (int j = 0; j < 4; ++j) {
                float4 hv = *(const float4*)&hs[(nq << 2) + j][k];
                acc[j][0] += hv.x * w0.x + hv.y * w1.x + hv.z * w2.x + hv.w * w3.x;
                acc[j][1] += hv.x * w0.y + hv.y * w1.y + hv.z * w2.y + hv.w * w3.y;
                acc[j][2] += hv.x * w0.z + hv.y * w1.z + hv.z * w2.z + hv.w * w3.z;
                acc[j][3] += hv.x * w0.w + hv.y * w1.w + hv.z * w2.w + hv.w * w3.w;
            }
        }

        int c0 = coff + (cq << 2);
        float bq0 = bvec[c0], bq1 = bvec[c0 + 1], bq2 = bvec[c0 + 2], bq3 = bvec[c0 + 3];
        float as0 = att_s[c0], as1 = att_s[c0 + 1], as2 = att_s[c0 + 2], as3 = att_s[c0 + 3];
        float ad0 = att_d[c0], ad1 = att_d[c0 + 1], ad2 = att_d[c0 + 2], ad3 = att_d[c0 + 3];
        int head = c0 >> 4;
        #pragma unroll
        for (int j = 0; j < 4; ++j) {
            int n = nbase + (nq << 2) + j;
            float g0 = acc[j][0] + bq0, g1v = acc[j][1] + bq1;
            float g2 = acc[j][2] + bq2, g3v = acc[j][3] + bq3;
            float ps = g0 * as0 + g1v * as1 + g2 * as2 + g3v * as3;
            float pd = g0 * ad0 + g1v * ad1 + g2 * ad2 + g3v * ad3;
            ps += __shfl_xor(ps, 1); ps += __shfl_xor(ps, 2);
            pd += __shfl_xor(pd, 1); pd += __shfl_xor(pd, 2);
            if (n < N_NODES) {
                union { __half2 h2[2]; uint2 u; } pk;
                pk.h2[0] = __floats2half2_rn(g0, g1v);
                pk.h2[1] = __floats2half2_rn(g2, g3v);
                *(uint2*)&g[(size_t)n * HD + c0] = pk.u;
                if ((cq & 3) == 0) {
                    a_src[(size_t)n * H_HEADS + head] = ps;
                    a_dst[(size_t)n * H_HEADS + head] = pd;
                }
            }
        }
    }
}

// ---------------------------------------------------------------------------
// CSR build v3 (4 kernels, zero scattered global atomics):
// epart_count -> escan -> epart_write -> bucket_build (row_ptr + col).
// ---------------------------------------------------------------------------
__global__ __launch_bounds__(256) void epart_count_kernel(
        const int* __restrict__ ei, int* __restrict__ bcountE) {
    __shared__ int lh[NB_E];
    int b = blockIdx.x, t = threadIdx.x;
    int lo = b * CH_E, hi = min(lo + CH_E, E_EDGES);
    for (int i = t; i < NB_E; i += 256) lh[i] = 0;
    __syncthreads();
    for (int e = lo + t; e < hi; e += 256)
        atomicAdd(&lh[ei[E_EDGES + e] >> 9], 1);
    __syncthreads();
    for (int i = t; i < NB_E; i += 256) bcountE[i * EB + b] = lh[i];
}

__global__ __launch_bounds__(1024) void escan_kernel(
        const int* __restrict__ bcountE, int* __restrict__ ebaseBB) {
    __shared__ int part[1024];
    int t = threadIdx.x;
    int lo = t * 25, hi = min(lo + 25, NBB);
    int s = 0;
    for (int i = lo; i < hi; ++i) s += bcountE[i];
    part[t] = s;
    __syncthreads();
    int val = s;
    for (int off = 1; off < 1024; off <<= 1) {
        int o = (t >= off) ? part[t - off] : 0;
        __syncthreads();
        val += o;
        part[t] = val;
        __syncthreads();
    }
    int run = val - s;
    for (int i = lo; i < hi; ++i) { ebaseBB[i] = run; run += bcountE[i]; }
}

__global__ __launch_bounds__(256) void epart_write_kernel(
        const int* __restrict__ ei, const int* __restrict__ ebaseBB,
        int* __restrict__ epack) {
    __shared__ int lbase[NB_E];
    int b = blockIdx.x, t = threadIdx.x;
    int lo = b * CH_E, hi = min(lo + CH_E, E_EDGES);
    for (int i = t; i < NB_E; i += 256) lbase[i] = ebaseBB[i * EB + b];
    __syncthreads();
    for (int e = lo + t; e < hi; e += 256) {
        int s = ei[e], d = ei[E_EDGES + e];
        int p = atomicAdd(&lbase[d >> 9], 1);       // LDS atomic
        epack[p] = (s << 9) | (d & 511);
    }
}

// One block per bucket: LDS dst-histogram -> local scan -> row_ptr write ->
// edge ranking -> col write (all within a 32 KB L2-resident window).
__global__ __launch_bounds__(256) void bucket_build_kernel(
        const int* __restrict__ ebaseBB, const int* __restrict__ epack,
        int* __restrict__ row_ptr, int* __restrict__ col) {
    __shared__ int lh[512];
    __shared__ int sc[256];
    __shared__ int lfill[512];
    int b = blockIdx.x, t = threadIdx.x;
    int lo = ebaseBB[b * EB];
    int hi = (b == NB_E - 1) ? E_EDGES : ebaseBB[(b + 1) * EB];
    lh[t] = 0; lh[t + 256] = 0;
    __syncthreads();
    for (int i = lo + t; i < hi; i += 256)
        atomicAdd(&lh[epack[i] & 511], 1);
    __syncthreads();
    int c0 = lh[2 * t], c1 = lh[2 * t + 1];
    int pairSum = c0 + c1;
    sc[t] = pairSum;
    __syncthreads();
    int val = pairSum;
    for (int off = 1; off < 256; off <<= 1) {
        int o = (t >= off) ? sc[t - off] : 0;
        __syncthreads();
        val += o;
        sc[t] = val;
        __syncthreads();
    }
    int excl2 = val - pairSum;
    int p0 = lo + excl2, p1 = lo + excl2 + c0;
    lfill[2 * t] = p0;
    lfill[2 * t + 1] = p1;
    int nb0 = b * 512;
    if (nb0 + 2 * t     <= N_NODES) row_ptr[nb0 + 2 * t]     = p0;
    if (nb0 + 2 * t + 1 <= N_NODES) row_ptr[nb0 + 2 * t + 1] = p1;
    __syncthreads();
    for (int i = lo + t; i < hi; i += 256) {
        int v = epack[i];
        int p = atomicAdd(&lfill[v & 511], 1);      // LDS atomic
        col[p] = ((unsigned)v) >> 9;
    }
}

// ---------------------------------------------------------------------------
// Degree-bucket counting sort of dst nodes (deg from row_ptr diffs).
// ---------------------------------------------------------------------------
__global__ __launch_bounds__(256) void bucket_hist_kernel(
        const int* __restrict__ row_ptr, int* __restrict__ bcount) {
    __shared__ int lh[64];
    int b = blockIdx.x, t = threadIdx.x;
    if (t < 64) lh[t] = 0;
    __syncthreads();
    int lo = b * SCAN_CH, hi = min(lo + SCAN_CH, N_NODES);
    for (int i = lo + t; i < hi; i += 256) {
        int dg = row_ptr[i + 1] - row_ptr[i];
        atomicAdd(&lh[min(dg, 63)], 1);
    }
    __syncthreads();
    if (t < 64) bcount[t * SCAN_BLOCKS + b] = lh[t];   // bucket-major
}

__global__ __launch_bounds__(1024) void bucket_scan_kernel(
        const int* __restrict__ bcount, int* __restrict__ boffs) {
    __shared__ int part[1024];
    int t = threadIdx.x;
    int base = t * 16;                       // 16384 = 64 buckets x 256 blocks
    int v[16]; int s = 0;
    #pragma unroll
    for (int k = 0; k < 16; ++k) { v[k] = bcount[base + k]; s += v[k]; }
    part[t] = s;
    __syncthreads();
    int val = s;
    for (int off = 1; off < 1024; off <<= 1) {
        int o = (t >= off) ? part[t - off] : 0;
        __syncthreads();
        val += o;
        part[t] = val;
        __syncthreads();
    }
    int run = val - s;
    #pragma unroll
    for (int k = 0; k < 16; ++k) { boffs[base + k] = run; run += v[k]; }
}

__global__ __launch_bounds__(256) void bucket_scatter_kernel(
        const int* __restrict__ row_ptr, const int* __restrict__ boffs,
        int* __restrict__ perm) {
    __shared__ int lbase[64];
    int b = blockIdx.x, t = threadIdx.x;
    if (t < 64) lbase[t] = boffs[t * SCAN_BLOCKS + b];
    __syncthreads();
    int lo = b * SCAN_CH, hi = min(lo + SCAN_CH, N_NODES);
    for (int i = lo + t; i < hi; i += 256) {
        int dg = row_ptr[i + 1] - row_ptr[i];
        int p = atomicAdd(&lbase[min(dg, 63)], 1);   // LDS atomic only
        perm[p] = i;
    }
}

// ---------------------------------------------------------------------------
// Layer-0 aggregation: aggregate h0 DIRECTLY (32 B rows, 3.2 MB L2-resident).
// ---------------------------------------------------------------------------
__global__ __launch_bounds__(256) void gat_aggr0_kernel(
        const int* __restrict__ perm,
        const int* __restrict__ row_ptr, const int* __restrict__ col,
        const float* __restrict__ a_src, const float* __restrict__ a_dst,
        const __half* __restrict__ h0, __half* __restrict__ m) {
    int wv = threadIdx.x >> 6, lane = threadIdx.x & 63;
    int grp = lane >> 4;
    int sub = lane & 15;
    int cq = sub & 3;
    int hp = sub >> 2;
    int slot = blockIdx.x * 16 + wv * 4 + grp;
    bool dvalid = slot < N_NODES;
    int d = perm[dvalid ? slot : N_NODES - 1];

    int i0 = row_ptr[d], end = row_ptr[d + 1];
    int deg = dvalid ? (end - i0) : 0;
    float2 ad = *(const float2*)(a_dst + (size_t)d * 8 + 2 * hp);

    float acc0[4], acc1[4];
    float den0, den1;
    {   // self loop
        float2 as = *(const float2*)(a_src + (size_t)d * 8 + 2 * hp);
        float l0 = as.x + ad.x; l0 = fmaxf(l0, NEG_SLOPE * l0);
        float l1 = as.y + ad.y; l1 = fmaxf(l1, NEG_SLOPE * l1);
        float w0 = __expf(l0), w1 = __expf(l1);
        uint2 hv = *(const uint2*)(h0 + (size_t)d * D_DIM + 4 * cq);
        float2 fa = __half22float2(*(__half2*)&hv.x);
        float2 fb = __half22float2(*(__half2*)&hv.y);
        acc0[0] = w0 * fa.x; acc0[1] = w0 * fa.y;
        acc0[2] = w0 * fb.x; acc0[3] = w0 * fb.y;
        acc1[0] = w1 * fa.x; acc1[1] = w1 * fa.y;
        acc1[2] = w1 * fb.x; acc1[3] = w1 * fb.y;
        den0 = w0; den1 = w1;
    }

    int md = deg;
    md = max(md, __shfl_xor(md, 16));
    md = max(md, __shfl_xor(md, 32));

    int colv = 0;
    #define EDGE_K(EL)                                                       \
    {                                                                        \
        int el_ = (EL);                                                      \
        int s = __shfl(colv, (grp << 4) | (el_ & 15));                       \
        float2 as = *(const float2*)(a_src + (size_t)s * 8 + 2 * hp);        \
        float l0 = as.x + ad.x; l0 = fmaxf(l0, NEG_SLOPE * l0);              \
        float l1 = as.y + ad.y; l1 = fmaxf(l1, NEG_SLOPE * l1);              \
        float w0 = (el_ < deg) ? __expf(l0) : 0.f;                           \
        float w1 = (el_ < deg) ? __expf(l1) : 0.f;                           \
        uint2 hv = *(const uint2*)(h0 + (size_t)s * D_DIM + 4 * cq);         \
        float2 fa = __half22float2(*(__half2*)&hv.x);                        \
        float2 fb = __half22float2(*(__half2*)&hv.y);                        \
        acc0[0] += w0 * fa.x; acc0[1] += w0 * fa.y;                          \
        acc0[2] += w0 * fb.x; acc0[3] += w0 * fb.y;                          \
        acc1[0] += w1 * fa.x; acc1[1] += w1 * fa.y;                          \
        acc1[2] += w1 * fb.x; acc1[3] += w1 * fb.y;                          \
        den0 += w0; den1 += w1;                                              \
    }

    for (int el = 0; el < md; el += 4) {
        if ((el & 15) == 0) {
            int ci = i0 + el + sub;
            ci = min(ci, end - 1);
            ci = max(ci, 0);
            colv = col[ci];
        }
        EDGE_K(el);
        EDGE_K(el + 1);
        EDGE_K(el + 2);
        EDGE_K(el + 3);
    }
    #undef EDGE_K

    float inv0 = 1.f / (den0 + 1e-16f);
    float inv1 = 1.f / (den1 + 1e-16f);
    if (dvalid) {
        union { __half2 h2[2]; uint2 u; } p0, p1;
        p0.h2[0] = __floats2half2_rn(acc0[0] * inv0, acc0[1] * inv0);
        p0.h2[1] = __floats2half2_rn(acc0[2] * inv0, acc0[3] * inv0);
        p1.h2[0] = __floats2half2_rn(acc1[0] * inv1, acc1[1] * inv1);
        p1.h2[1] = __floats2half2_rn(acc1[2] * inv1, acc1[3] * inv1);
        *(uint2*)(m + (size_t)d * HD + (2 * hp) * 16 + 4 * cq)       = p0.u;
        *(uint2*)(m + (size_t)d * HD + (2 * hp + 1) * 16 + 4 * cq)   = p1.u;
    }
}

// ---------------------------------------------------------------------------
// Layer-1 aggregation over CSR + fused heads.
// ---------------------------------------------------------------------------
__global__ __launch_bounds__(256) void gat_aggr1_kernel(
        const int* __restrict__ perm,
        const int* __restrict__ row_ptr, const int* __restrict__ col,
        const float* __restrict__ a_src, const float* __restrict__ a_dst,
        const __half* __restrict__ g, const float* __restrict__ bias,
        float* __restrict__ out,
        const float* __restrict__ Wy1, const float* __restrict__ by1,
        const float* __restrict__ Wy0, const float* __restrict__ by0,
        const float* __restrict__ Wc1, const float* __restrict__ bc1,
        const float* __restrict__ Wc2, const float* __restrict__ bc2) {
    int wv = threadIdx.x >> 6, lane = threadIdx.x & 63;
    int grp = lane >> 4;
    int sub = lane & 15;
    int hh  = sub >> 1;
    int slot = blockIdx.x * 16 + wv * 4 + grp;
    bool dvalid = slot < N_NODES;
    int d = perm[dvalid ? slot : N_NODES - 1];

    int i0 = row_ptr[d], end = row_ptr[d + 1];
    int deg = dvalid ? (end - i0) : 0;
    float ad = a_dst[d * 8 + hh];

    float acc[8];
    float den;
    {
        float a = a_src[d * 8 + hh] + ad;
        a = fmaxf(a, NEG_SLOPE * a);
        float w = __expf(a);
        uint4 rv = *(const uint4*)(g + (size_t)d * HD + (sub << 3));
        float2 f0 = __half22float2(*(__half2*)&rv.x);
        float2 f1 = __half22float2(*(__half2*)&rv.y);
        float2 f2 = __half22float2(*(__half2*)&rv.z);
        float2 f3 = __half22float2(*(__half2*)&rv.w);
        acc[0] = w * f0.x; acc[1] = w * f0.y;
        acc[2] = w * f1.x; acc[3] = w * f1.y;
        acc[4] = w * f2.x; acc[5] = w * f2.y;
        acc[6] = w * f3.x; acc[7] = w * f3.y;
        den = w;
    }

    int md = deg;
    md = max(md, __shfl_xor(md, 16));
    md = max(md, __shfl_xor(md, 32));

    int colv = 0;
    #define EDGE_K(EL)                                                       \
    {                                                                        \
        int el_ = (EL);                                                      \
        int s = __shfl(colv, (grp << 4) | (el_ & 15));                       \
        float a = a_src[s * 8 + hh] + ad;                                    \
        a = fmaxf(a, NEG_SLOPE * a);                                         \
        float w = (el_ < deg) ? __expf(a) : 0.f;                             \
        uint4 rv = *(const uint4*)(g + (size_t)s * HD + (sub << 3));         \
        float2 f0 = __half22float2(*(__half2*)&rv.x);                        \
        float2 f1 = __half22float2(*(__half2*)&rv.y);                        \
        float2 f2 = __half22float2(*(__half2*)&rv.z);                        \
        float2 f3 = __half22float2(*(__half2*)&rv.w);                        \
        acc[0] += w * f0.x; acc[1] += w * f0.y;                              \
        acc[2] += w * f1.x; acc[3] += w * f1.y;                              \
        acc[4] += w * f2.x; acc[5] += w * f2.y;                              \
        acc[6] += w * f3.x; acc[7] += w * f3.y;                              \
        den += w;                                                            \
    }

    for (int el = 0; el < md; el += 4) {
        if ((el & 15) == 0) {
            int ci = i0 + el + sub;
            ci = min(ci, end - 1);
            ci = max(ci, 0);
            colv = col[ci];
        }
        EDGE_K(el);
        EDGE_K(el + 1);
        EDGE_K(el + 2);
        EDGE_K(el + 3);
    }
    #undef EDGE_K

    float inv = 1.f / (den + 1e-16f);
    int c0 = sub << 3;
    float h[8];
    #pragma unroll
    for (int k = 0; k < 8; ++k) h[k] = acc[k] * inv + bias[c0 + k];

    // causal effect: width-16 reduction within the group
    float p = 0.f;
    #pragma unroll
    for (int k = 0; k < 8; ++k)
        p += h[k] * (Wy1[c0 + k] - Wy0[c0 + k]);
    p += __shfl_xor(p, 1); p += __shfl_xor(p, 2);
    p += __shfl_xor(p, 4); p += __shfl_xor(p, 8);
    // classifier MLP
    float acc2 = 0.f;
    #pragma unroll
    for (int j = 0; j < D_DIM; ++j) {
        float q = 0.f;
        #pragma unroll
        for (int k = 0; k < 8; ++k)
            q += h[k] * Wc1[(c0 + k) * D_DIM + j];
        q += __shfl_xor(q, 1); q += __shfl_xor(q, 2);
        q += __shfl_xor(q, 4); q += __shfl_xor(q, 8);
        float z = q + bc1[j];
        z = (z > 0.f) ? z : 0.f;
        acc2 += z * Wc2[j];
    }
    if (sub == 0 && dvalid) {
        out[d] = p + by1[0] - by0[0];
        out[N_NODES + d] = 1.f / (1.f + __expf(-(acc2 + bc2[0])));
    }
}

// ---------------------------------------------------------------------------
extern "C" void kernel_launch(void* const* d_in, const int* in_sizes, int n_in,
                              void* d_out, int out_size, void* d_ws, size_t ws_size,
                              hipStream_t stream) {
    const float* x     = (const float*)d_in[0];
    const int*   ei    = (const int*)  d_in[1];
    const float* W_emb = (const float*)d_in[2];
    const float* b_emb = (const float*)d_in[3];
    const float* W0    = (const float*)d_in[4];
    const float* as0   = (const float*)d_in[5];
    const float* ad0   = (const float*)d_in[6];
    const float* b0    = (const float*)d_in[7];
    const float* W1    = (const float*)d_in[8];
    const float* as1   = (const float*)d_in[9];
    const float* ad1   = (const float*)d_in[10];
    const float* b1    = (const float*)d_in[11];
    const float* Wy1   = (const float*)d_in[12];
    const float* by1   = (const float*)d_in[13];
    const float* Wy0   = (const float*)d_in[14];
    const float* by0   = (const float*)d_in[15];
    const float* Wc1   = (const float*)d_in[16];
    const float* bc1   = (const float*)d_in[17];
    const float* Wc2   = (const float*)d_in[18];
    const float* bc2   = (const float*)d_in[19];
    float* out = (float*)d_out;

    float* ws    = (float*)d_ws;
    __half* mH   = (__half*)ws;                              // N*128 half
    __half* gH   = (__half*)(ws + (size_t)N_NODES * 64);     // N*128 half
    __half* h0h  = (__half*)(ws + (size_t)N_NODES * 128);    // N*16 half
    float* a_s   = ws + (size_t)N_NODES * 136;               // N*8
    float* a_d   = a_s + (size_t)N_NODES * 8;                // N*8
    float* Wf    = a_d + (size_t)N_NODES * 8;                // 16384
    float* u_s   = Wf + 16384;                               // 128
    float* u_d   = u_s + 128;                                // 128
    float* bvec  = u_d + 128;                                // 128
    int*   row_ptr = (int*)(bvec + 128);                     // N+1
    int*   bcountE = row_ptr + (N_NODES + 1);                // 25088
    int*   ebaseBB = bcountE + NBB;                          // 25088
    int*   bcount  = ebaseBB + NBB;                          // 16384
    int*   boffs   = bcount + 64 * SCAN_BLOCKS;              // 16384
    int*   perm    = boffs + 64 * SCAN_BLOCKS;               // N
    int*   col     = perm + N_NODES;                         // E
    int*   epack   = col + E_EDGES;                          // E

    int aggrBlocks = (N_NODES + 15) / 16;

    // ----- CSR build v3 (4 kernels) -----
    hipLaunchKernelGGL(epart_count_kernel, dim3(EB), dim3(256), 0, stream,
                       ei, bcountE);
    hipLaunchKernelGGL(escan_kernel, dim3(1), dim3(1024), 0, stream,
                       bcountE, ebaseBB);
    hipLaunchKernelGGL(epart_write_kernel, dim3(EB), dim3(256), 0, stream,
                       ei, ebaseBB, epack);
    hipLaunchKernelGGL(bucket_build_kernel, dim3(NB_E), dim3(256), 0, stream,
                       ebaseBB, epack, row_ptr, col);

    // ----- degree-bucket sort of dsts (deg from row_ptr diffs) -----
    hipLaunchKernelGGL(bucket_hist_kernel, dim3(SCAN_BLOCKS), dim3(256), 0, stream,
                       row_ptr, bcount);
    hipLaunchKernelGGL(bucket_scan_kernel, dim3(1), dim3(1024), 0, stream,
                       bcount, boffs);
    hipLaunchKernelGGL(bucket_scatter_kernel, dim3(SCAN_BLOCKS), dim3(256), 0, stream,
                       row_ptr, boffs, perm);

    // ----- Embedding (fp16 h0) + fused-weight precompute -----
    hipLaunchKernelGGL(embed_kernel, dim3(512), dim3(256), 0, stream,
                       x, W_emb, b_emb, h0h);
    hipLaunchKernelGGL(precompute_kernel, dim3(1), dim3(256), 0, stream,
                       W0, W1, as0, ad0, b0, Wf, u_s, u_d, bvec);

    // ----- Layer 0: attention dots from h0, aggregate h0 -> m -----
    hipLaunchKernelGGL(attdot0_kernel, dim3((N_NODES * 8 + 255) / 256), dim3(256),
                       0, stream, h0h, u_s, u_d, a_s, a_d);
    hipLaunchKernelGGL(gat_aggr0_kernel, dim3(aggrBlocks), dim3(256), 0, stream,
                       perm, row_ptr, col, a_s, a_d, h0h, mH);

    // ----- Layer 1: fused transform (m @ W_fused + bvec) + aggregation -----
    hipLaunchKernelGGL(transform_fused_kernel, dim3(1024), dim3(256), 0, stream,
                       mH, Wf, bvec, as1, ad1, gH, a_s, a_d);
    hipLaunchKernelGGL(gat_aggr1_kernel, dim3(aggrBlocks), dim3(256), 0, stream,
                       perm, row_ptr, col, a_s, a_d, gH, b1, out,
                       Wy1, by1, Wy0, by0, Wc1, bc1, Wc2, bc2);
}